// Round 1
// baseline (567.935 us; speedup 1.0000x reference)
//
#include <hip/hip_runtime.h>
#include <cstdint>
#include <cstddef>

typedef __attribute__((ext_vector_type(8))) short short8;
typedef __attribute__((ext_vector_type(4))) float float4x;

__device__ __forceinline__ uint16_t f2b(float f){
  uint32_t u = __builtin_bit_cast(uint32_t, f);
  u += 0x7FFFu + ((u >> 16) & 1u);
  return (uint16_t)(u >> 16);
}
__device__ __forceinline__ float b2f(uint16_t h){
  uint32_t u = ((uint32_t)h) << 16;
  return __builtin_bit_cast(float, u);
}
__device__ __forceinline__ float4x zero4(){
  float4x v; v[0]=0.f; v[1]=0.f; v[2]=0.f; v[3]=0.f; return v;
}
// async global->LDS, 16B per lane. LDS dest = wave-uniform base + lane*16.
__device__ __forceinline__ void gload16(const uint16_t* g, uint16_t* l){
  __builtin_amdgcn_global_load_lds(
      (const __attribute__((address_space(1))) uint32_t*)g,
      (__attribute__((address_space(3))) uint32_t*)l, 16, 0, 0);
}

// ---------------- x (f32) -> bf16 ----------------
__global__ __launch_bounds__(256) void k_f32_to_bf16(const float* __restrict__ in,
                                                     uint16_t* __restrict__ out, int n4){
  int i = blockIdx.x * 256 + threadIdx.x;
  if (i < n4){
    float4 v = ((const float4*)in)[i];
    ushort4 o;
    o.x = f2b(v.x); o.y = f2b(v.y); o.z = f2b(v.z); o.w = f2b(v.w);
    ((ushort4*)out)[i] = o;
  }
}

// ---------------- W [K][N] f32 -> Wt [N][K] bf16 ----------------
__global__ __launch_bounds__(256) void k_transpose_bf16(const float* __restrict__ W,
                                                        uint16_t* __restrict__ Wt, int K, int N){
  __shared__ float tile[32][33];
  int k0 = blockIdx.y * 32, n0 = blockIdx.x * 32;
  int c = threadIdx.x & 31, r0 = threadIdx.x >> 5;
  for (int rr = r0; rr < 32; rr += 8)
    tile[rr][c] = W[(size_t)(k0 + rr) * N + n0 + c];
  __syncthreads();
  for (int rr = r0; rr < 32; rr += 8)
    Wt[(size_t)(n0 + rr) * K + k0 + c] = f2b(tile[c][rr]);
}

// ---------------- bf16 GEMM: C = A[m][k] * Bt[n][k] + bias, 128x128 tile ----------------
template<int OUTF>
__global__ __launch_bounds__(256, 3) void k_gemm_bt(const uint16_t* __restrict__ A,
                                                    const uint16_t* __restrict__ Bt,
                                                    const float* __restrict__ bias,
                                                    void* __restrict__ Cout,
                                                    int M, int N, int K){
  __shared__ __align__(16) uint16_t As[2][128*32];
  __shared__ __align__(16) uint16_t Bs[2][128*32];
  const int tid = threadIdx.x, lane = tid & 63, wave = tid >> 6;
  const int wr = wave >> 1, wc = wave & 1;
  const int m0 = blockIdx.y * 128, n0 = blockIdx.x * 128;
  const int quad = lane >> 4, l15 = lane & 15;
  const int rowA = tid >> 2, chA = tid & 3;

  float4x acc[4][4];
  for (int i = 0; i < 4; i++) for (int j = 0; j < 4; j++) acc[i][j] = zero4();

  const uint16_t* pa0 = &A[(size_t)(m0 + rowA)*K + chA*8];
  const uint16_t* pa1 = &A[(size_t)(m0 + rowA + 64)*K + chA*8];
  const uint16_t* pb0 = &Bt[(size_t)(n0 + rowA)*K + chA*8];
  const uint16_t* pb1 = &Bt[(size_t)(n0 + rowA + 64)*K + chA*8];

  gload16(pa0, &As[0][tid*8]);
  gload16(pa1, &As[0][64*32 + tid*8]);
  gload16(pb0, &Bs[0][tid*8]);
  gload16(pb1, &Bs[0][64*32 + tid*8]);

  int buf = 0;
  for (int k0 = 0; k0 < K; k0 += 32){
    __syncthreads();
    if (k0 + 32 < K){
      int nb = buf ^ 1;
      gload16(pa0 + k0 + 32, &As[nb][tid*8]);
      gload16(pa1 + k0 + 32, &As[nb][64*32 + tid*8]);
      gload16(pb0 + k0 + 32, &Bs[nb][tid*8]);
      gload16(pb1 + k0 + 32, &Bs[nb][64*32 + tid*8]);
    }
    short8 af[4], bf[4];
#pragma unroll
    for (int mt = 0; mt < 4; mt++)
      af[mt] = *(const short8*)&As[buf][(wr*64 + mt*16 + l15)*32 + quad*8];
#pragma unroll
    for (int nt = 0; nt < 4; nt++)
      bf[nt] = *(const short8*)&Bs[buf][(wc*64 + nt*16 + l15)*32 + quad*8];
#pragma unroll
    for (int mt = 0; mt < 4; mt++)
#pragma unroll
      for (int nt = 0; nt < 4; nt++)
        acc[mt][nt] = __builtin_amdgcn_mfma_f32_16x16x32_bf16(af[mt], bf[nt], acc[mt][nt], 0, 0, 0);
    buf ^= 1;
  }

#pragma unroll
  for (int mt = 0; mt < 4; mt++){
    int grow = m0 + wr*64 + mt*16 + quad*4;
#pragma unroll
    for (int nt = 0; nt < 4; nt++){
      int gcol = n0 + wc*64 + nt*16 + l15;
      float bv = bias[gcol];
#pragma unroll
      for (int r = 0; r < 4; r++){
        float v = acc[mt][nt][r] + bv;
        if (OUTF) ((float*)Cout)[(size_t)(grow + r)*N + gcol] = v;
        else      ((uint16_t*)Cout)[(size_t)(grow + r)*N + gcol] = f2b(v);
      }
    }
  }
}

// ---------------- RoPE in-place on q,k halves of qkv [BT][3072] bf16 ----------------
__global__ __launch_bounds__(256) void k_rope(uint16_t* __restrict__ qkv){
  int idx = blockIdx.x * 256 + threadIdx.x;     // 2^23 items
  int i = idx & 31;
  int h = (idx >> 5) & 15;
  int t = (idx >> 9) & 2047;
  int b = (idx >> 20) & 3;
  int which = idx >> 22;                        // 0=q, 1=k
  size_t base = ((size_t)(b*2048 + t))*3072 + (size_t)which*1024 + h*64 + i;
  float u1 = b2f(qkv[base]), u2 = b2f(qkv[base + 32]);
  float inv = exp2f(-(float)i * 0.4152410118609203f);  // 10000^(-i/32)
  float ang = (float)t * inv;
  float s, c;
  __sincosf(ang, &s, &c);
  qkv[base]      = f2b(u1*c - u2*s);
  qkv[base + 32] = f2b(u2*c + u1*s);
}

// ---------------- V [t][d] -> Vt [bh][d][t] bf16 ----------------
__global__ __launch_bounds__(256) void k_transpose_v(const uint16_t* __restrict__ qkv,
                                                     uint16_t* __restrict__ vt){
  __shared__ __align__(16) uint16_t tile[64*72];
  int bh = blockIdx.y;
  int t0 = blockIdx.x * 64;
  int b = bh >> 4, h = bh & 15;
  int r = threadIdx.x >> 2, ch = threadIdx.x & 3;
  const uint16_t* src = &qkv[((size_t)(b*2048 + t0 + r))*3072 + 2048 + h*64];
  *(uint4*)&tile[r*72 + ch*8]      = *(const uint4*)&src[ch*8];
  *(uint4*)&tile[r*72 + 32 + ch*8] = *(const uint4*)&src[32 + ch*8];
  __syncthreads();
  short8 v0, v1;
#pragma unroll
  for (int j = 0; j < 8; j++) v0[j] = (short)tile[(ch*8 + j)*72 + r];
#pragma unroll
  for (int j = 0; j < 8; j++) v1[j] = (short)tile[(32 + ch*8 + j)*72 + r];
  uint16_t* dst = &vt[((size_t)(bh*64 + r))*2048 + t0];
  *(short8*)&dst[ch*8]      = v0;
  *(short8*)&dst[32 + ch*8] = v1;
}

// ---------------- flash attention, fixed-max softmax, parity-split pair-per-2-waves ----------------
// grid (16, 64). Block x holds pairs p = 2x (waves 0,1) and p = 2x+1 (waves 2,3).
// Each pair is processed by TWO waves splitting the kt tile loop by parity
// (wave e handles kt = e, e+2, ...). Fixed-max softmax makes partial o/l plain
// sums -> partners combine additively through LDS. Chunks c = p and 63-p give
// identical ktmax for both pairs in a block, so barriers stay aligned.
// 1024 blocks -> 4 blocks/CU -> 4 waves/SIMD (2x the previous occupancy).
__global__ __launch_bounds__(256, 4) void k_attn(const uint16_t* __restrict__ qkv,
                                                 const uint16_t* __restrict__ vt,
                                                 uint16_t* __restrict__ y){
  __shared__ __align__(16) uint16_t Ps[128*72];   // per-wave P staging (18432 B)
  __shared__ float Cmb[2][32*65];                 // per-pair o combine (16640 B)
  __shared__ float Lmb[2][32*17];                 // per-pair l combine (4352 B)
  const int w = threadIdx.x >> 6;
  const int e  = w & 1;                           // kt parity this wave owns
  const int pr = w >> 1;                          // pair slot in block (0/1)
  const int p  = blockIdx.x*2 + pr;               // global pair 0..31
  const int bh = blockIdx.y;
  const int b = bh >> 4, h = bh & 15;
  const int lane = threadIdx.x & 63;
  const int quad = lane >> 4, l15 = lane & 15;
  uint16_t* Pw = &Ps[w*32*72];                    // wave-private P region

  const uint16_t* Qbase = qkv + (size_t)b*2048*3072 + h*64;
  const uint16_t* Kbase = qkv + (size_t)b*2048*3072 + 1024 + h*64;
  const uint16_t* Vbase = vt  + (size_t)bh*64*2048;
  const float M = 30.0f;                          // fixed softmax shift (cancels exactly)

  for (int cc = 0; cc < 2; cc++){
    const int c = cc ? (63 - p) : p;              // q-chunk 0..63
    const int r0 = c*32;
    const int ktmax = c >> 1;

    // Q fragments (held in registers for this chunk)
    short8 aq[2][2];
#pragma unroll
    for (int mt = 0; mt < 2; mt++)
#pragma unroll
      for (int hf = 0; hf < 2; hf++)
        aq[mt][hf] = *(const short8*)&Qbase[(size_t)(r0 + mt*16 + l15)*3072 + hf*32 + quad*8];

    float4x o[2][4];
#pragma unroll
    for (int mt = 0; mt < 2; mt++) for (int nt = 0; nt < 4; nt++) o[mt][nt] = zero4();
    float lrow[2][4];
#pragma unroll
    for (int mt = 0; mt < 2; mt++) for (int rr = 0; rr < 4; rr++) lrow[mt][rr] = 0.f;

    // first K tile of this wave's parity class (rows always < 2048, safe even if loop empty)
    short8 bk[4][2];
#pragma unroll
    for (int nt = 0; nt < 4; nt++)
#pragma unroll
      for (int hf = 0; hf < 2; hf++)
        bk[nt][hf] = *(const short8*)&Kbase[(size_t)(e*64 + nt*16 + l15)*3072 + hf*32 + quad*8];

    for (int kt = e; kt <= ktmax; kt += 2){
      // V fragments for this tile (used late -> latency overlapped)
      short8 bv[4][2];
#pragma unroll
      for (int nt = 0; nt < 4; nt++)
#pragma unroll
        for (int hf = 0; hf < 2; hf++)
          bv[nt][hf] = *(const short8*)&Vbase[(size_t)(nt*16 + l15)*2048 + kt*64 + hf*32 + quad*8];

      float4x s[2][4];
#pragma unroll
      for (int mt = 0; mt < 2; mt++) for (int nt = 0; nt < 4; nt++) s[mt][nt] = zero4();
#pragma unroll
      for (int nt = 0; nt < 4; nt++){
        s[0][nt] = __builtin_amdgcn_mfma_f32_16x16x32_bf16(aq[0][0], bk[nt][0], s[0][nt], 0, 0, 0);
        s[0][nt] = __builtin_amdgcn_mfma_f32_16x16x32_bf16(aq[0][1], bk[nt][1], s[0][nt], 0, 0, 0);
        s[1][nt] = __builtin_amdgcn_mfma_f32_16x16x32_bf16(aq[1][0], bk[nt][0], s[1][nt], 0, 0, 0);
        s[1][nt] = __builtin_amdgcn_mfma_f32_16x16x32_bf16(aq[1][1], bk[nt][1], s[1][nt], 0, 0, 0);
      }
      // prefetch next K tile of this parity (WAR on bk places these after the QK MFMAs)
      if (kt + 2 <= ktmax){
#pragma unroll
        for (int nt = 0; nt < 4; nt++)
#pragma unroll
          for (int hf = 0; hf < 2; hf++)
            bk[nt][hf] = *(const short8*)&Kbase[(size_t)((kt+2)*64 + nt*16 + l15)*3072 + hf*32 + quad*8];
      }

      // mask only on the diagonal tile (only the parity wave owning ktmax reaches it)
      if (kt == ktmax){
#pragma unroll
        for (int mt = 0; mt < 2; mt++)
#pragma unroll
          for (int nt = 0; nt < 4; nt++)
#pragma unroll
            for (int rr = 0; rr < 4; rr++){
              int tk = kt*64 + nt*16 + l15;
              int tq = r0 + mt*16 + quad*4 + rr;
              if (tk > tq) s[mt][nt][rr] = -1e30f;
            }
      }
      // p = exp(s*0.125 - M); accumulate per-lane row sums; P -> LDS (bf16, A-layout via roundtrip)
#pragma unroll
      for (int mt = 0; mt < 2; mt++)
#pragma unroll
        for (int nt = 0; nt < 4; nt++)
#pragma unroll
          for (int rr = 0; rr < 4; rr++){
            float pv = __expf(__builtin_fmaf(s[mt][nt][rr], 0.125f, -M));
            lrow[mt][rr] += pv;
            Pw[(mt*16 + quad*4 + rr)*72 + nt*16 + l15] = f2b(pv);
          }
#pragma unroll
      for (int mt = 0; mt < 2; mt++){
        short8 ap0 = *(const short8*)&Pw[(mt*16 + l15)*72 + quad*8];
        short8 ap1 = *(const short8*)&Pw[(mt*16 + l15)*72 + 32 + quad*8];
#pragma unroll
        for (int nt = 0; nt < 4; nt++){
          o[mt][nt] = __builtin_amdgcn_mfma_f32_16x16x32_bf16(ap0, bv[nt][0], o[mt][nt], 0, 0, 0);
          o[mt][nt] = __builtin_amdgcn_mfma_f32_16x16x32_bf16(ap1, bv[nt][1], o[mt][nt], 0, 0, 0);
        }
      }
    }

    // ---- cross-parity combine: partner partial sums add exactly (fixed M) ----
    if (e){
      float* Cb = Cmb[pr];
      float* Lb = Lmb[pr];
#pragma unroll
      for (int mt = 0; mt < 2; mt++)
#pragma unroll
        for (int nt = 0; nt < 4; nt++)
#pragma unroll
          for (int r = 0; r < 4; r++)
            Cb[(mt*16 + quad*4 + r)*65 + nt*16 + l15] = o[mt][nt][r];
#pragma unroll
      for (int mt = 0; mt < 2; mt++)
#pragma unroll
        for (int rr = 0; rr < 4; rr++)
          Lb[(mt*16 + quad*4 + rr)*17 + l15] = lrow[mt][rr];
    }
    __syncthreads();
    if (!e){
      const float* Cb = Cmb[pr];
      const float* Lb = Lmb[pr];
#pragma unroll
      for (int mt = 0; mt < 2; mt++)
#pragma unroll
        for (int nt = 0; nt < 4; nt++)
#pragma unroll
          for (int r = 0; r < 4; r++)
            o[mt][nt][r] += Cb[(mt*16 + quad*4 + r)*65 + nt*16 + l15];
#pragma unroll
      for (int mt = 0; mt < 2; mt++)
#pragma unroll
        for (int rr = 0; rr < 4; rr++)
          lrow[mt][rr] += Lb[(mt*16 + quad*4 + rr)*17 + l15];

      // one-time l reduction across the 16-lane dim, then output
#pragma unroll
      for (int mt = 0; mt < 2; mt++)
#pragma unroll
        for (int rr = 0; rr < 4; rr++){
          float sm = lrow[mt][rr];
          for (int d = 1; d < 16; d <<= 1) sm += __shfl_xor(sm, d);
          float linv = 1.f / sm;
          int tq = r0 + mt*16 + quad*4 + rr;
          size_t rowbase = ((size_t)(b*2048 + tq))*1024 + h*64;
#pragma unroll
          for (int nt = 0; nt < 4; nt++)
            y[rowbase + nt*16 + l15] = f2b(o[mt][nt][rr] * linv);
        }
    }
    __syncthreads();   // protect combine buffers before next chunk reuses them
  }
}

extern "C" void kernel_launch(void* const* d_in, const int* in_sizes, int n_in,
                              void* d_out, int out_size, void* d_ws, size_t ws_size,
                              hipStream_t stream){
  const float* x     = (const float*)d_in[0];
  const float* Wqkv  = (const float*)d_in[1];
  const float* bqkv  = (const float*)d_in[2];
  const float* Wproj = (const float*)d_in[3];
  const float* bproj = (const float*)d_in[4];

  uint16_t* p = (uint16_t*)d_ws;
  uint16_t* xb    = p; p += (size_t)8192*1024;   // x in bf16
  uint16_t* wqkvt = p; p += (size_t)3072*1024;   // W_qkv^T bf16
  uint16_t* wprjt = p; p += (size_t)1024*1024;   // W_proj^T bf16
  uint16_t* qkv   = p; p += (size_t)8192*3072;   // qkv (rope'd in place)
  uint16_t* vt    = p; p += (size_t)64*64*2048;  // V^T per head [bh][d][t]
  uint16_t* yb    = p; p += (size_t)8192*1024;   // attention output bf16

  k_f32_to_bf16<<<8192, 256, 0, stream>>>(x, xb, 2097152);
  k_transpose_bf16<<<dim3(96, 32), 256, 0, stream>>>(Wqkv, wqkvt, 1024, 3072);
  k_transpose_bf16<<<dim3(32, 32), 256, 0, stream>>>(Wproj, wprjt, 1024, 1024);
  k_gemm_bt<0><<<dim3(24, 64), 256, 0, stream>>>(xb, wqkvt, bqkv, (void*)qkv, 8192, 3072, 1024);
  k_rope<<<32768, 256, 0, stream>>>(qkv);
  k_transpose_v<<<dim3(32, 64), 256, 0, stream>>>(qkv, vt);
  k_attn<<<dim3(16, 64), 256, 0, stream>>>(qkv, vt, yb);
  k_gemm_bt<1><<<dim3(8, 64), 256, 0, stream>>>(yb, wprjt, bproj, d_out, 8192, 1024, 1024);
}

// Round 2
// 318.711 us; speedup vs baseline: 1.7820x; 1.7820x over previous
//
#include <hip/hip_runtime.h>
#include <cstdint>
#include <cstddef>

typedef __attribute__((ext_vector_type(8))) short short8;
typedef __attribute__((ext_vector_type(4))) float float4x;

__device__ __forceinline__ uint16_t f2b(float f){
  uint32_t u = __builtin_bit_cast(uint32_t, f);
  u += 0x7FFFu + ((u >> 16) & 1u);
  return (uint16_t)(u >> 16);
}
__device__ __forceinline__ float b2f(uint16_t h){
  uint32_t u = ((uint32_t)h) << 16;
  return __builtin_bit_cast(float, u);
}
__device__ __forceinline__ float4x zero4(){
  float4x v; v[0]=0.f; v[1]=0.f; v[2]=0.f; v[3]=0.f; return v;
}
// async global->LDS, 16B per lane. LDS dest = wave-uniform base + lane*16.
__device__ __forceinline__ void gload16(const uint16_t* g, uint16_t* l){
  __builtin_amdgcn_global_load_lds(
      (const __attribute__((address_space(1))) uint32_t*)g,
      (__attribute__((address_space(3))) uint32_t*)l, 16, 0, 0);
}

// ---------------- x (f32) -> bf16 ----------------
__global__ __launch_bounds__(256) void k_f32_to_bf16(const float* __restrict__ in,
                                                     uint16_t* __restrict__ out, int n4){
  int i = blockIdx.x * 256 + threadIdx.x;
  if (i < n4){
    float4 v = ((const float4*)in)[i];
    ushort4 o;
    o.x = f2b(v.x); o.y = f2b(v.y); o.z = f2b(v.z); o.w = f2b(v.w);
    ((ushort4*)out)[i] = o;
  }
}

// ---------------- W [K][N] f32 -> Wt [N][K] bf16 ----------------
__global__ __launch_bounds__(256) void k_transpose_bf16(const float* __restrict__ W,
                                                        uint16_t* __restrict__ Wt, int K, int N){
  __shared__ float tile[32][33];
  int k0 = blockIdx.y * 32, n0 = blockIdx.x * 32;
  int c = threadIdx.x & 31, r0 = threadIdx.x >> 5;
  for (int rr = r0; rr < 32; rr += 8)
    tile[rr][c] = W[(size_t)(k0 + rr) * N + n0 + c];
  __syncthreads();
  for (int rr = r0; rr < 32; rr += 8)
    Wt[(size_t)(n0 + rr) * K + k0 + c] = f2b(tile[c][rr]);
}

// ---------------- bf16 GEMM: C = A[m][k] * Bt[n][k] + bias, 128x128 tile ----------------
template<int OUTF>
__global__ __launch_bounds__(256, 3) void k_gemm_bt(const uint16_t* __restrict__ A,
                                                    const uint16_t* __restrict__ Bt,
                                                    const float* __restrict__ bias,
                                                    void* __restrict__ Cout,
                                                    int M, int N, int K){
  __shared__ __align__(16) uint16_t As[2][128*32];
  __shared__ __align__(16) uint16_t Bs[2][128*32];
  const int tid = threadIdx.x, lane = tid & 63, wave = tid >> 6;
  const int wr = wave >> 1, wc = wave & 1;
  const int m0 = blockIdx.y * 128, n0 = blockIdx.x * 128;
  const int quad = lane >> 4, l15 = lane & 15;
  const int rowA = tid >> 2, chA = tid & 3;

  float4x acc[4][4];
  for (int i = 0; i < 4; i++) for (int j = 0; j < 4; j++) acc[i][j] = zero4();

  const uint16_t* pa0 = &A[(size_t)(m0 + rowA)*K + chA*8];
  const uint16_t* pa1 = &A[(size_t)(m0 + rowA + 64)*K + chA*8];
  const uint16_t* pb0 = &Bt[(size_t)(n0 + rowA)*K + chA*8];
  const uint16_t* pb1 = &Bt[(size_t)(n0 + rowA + 64)*K + chA*8];

  gload16(pa0, &As[0][tid*8]);
  gload16(pa1, &As[0][64*32 + tid*8]);
  gload16(pb0, &Bs[0][tid*8]);
  gload16(pb1, &Bs[0][64*32 + tid*8]);

  int buf = 0;
  for (int k0 = 0; k0 < K; k0 += 32){
    __syncthreads();
    if (k0 + 32 < K){
      int nb = buf ^ 1;
      gload16(pa0 + k0 + 32, &As[nb][tid*8]);
      gload16(pa1 + k0 + 32, &As[nb][64*32 + tid*8]);
      gload16(pb0 + k0 + 32, &Bs[nb][tid*8]);
      gload16(pb1 + k0 + 32, &Bs[nb][64*32 + tid*8]);
    }
    short8 af[4], bf[4];
#pragma unroll
    for (int mt = 0; mt < 4; mt++)
      af[mt] = *(const short8*)&As[buf][(wr*64 + mt*16 + l15)*32 + quad*8];
#pragma unroll
    for (int nt = 0; nt < 4; nt++)
      bf[nt] = *(const short8*)&Bs[buf][(wc*64 + nt*16 + l15)*32 + quad*8];
#pragma unroll
    for (int mt = 0; mt < 4; mt++)
#pragma unroll
      for (int nt = 0; nt < 4; nt++)
        acc[mt][nt] = __builtin_amdgcn_mfma_f32_16x16x32_bf16(af[mt], bf[nt], acc[mt][nt], 0, 0, 0);
    buf ^= 1;
  }

#pragma unroll
  for (int mt = 0; mt < 4; mt++){
    int grow = m0 + wr*64 + mt*16 + quad*4;
#pragma unroll
    for (int nt = 0; nt < 4; nt++){
      int gcol = n0 + wc*64 + nt*16 + l15;
      float bv = bias[gcol];
#pragma unroll
      for (int r = 0; r < 4; r++){
        float v = acc[mt][nt][r] + bv;
        if (OUTF) ((float*)Cout)[(size_t)(grow + r)*N + gcol] = v;
        else      ((uint16_t*)Cout)[(size_t)(grow + r)*N + gcol] = f2b(v);
      }
    }
  }
}

// ---------------- RoPE in-place on q,k halves of qkv [BT][3072] bf16 ----------------
__global__ __launch_bounds__(256) void k_rope(uint16_t* __restrict__ qkv){
  int idx = blockIdx.x * 256 + threadIdx.x;     // 2^23 items
  int i = idx & 31;
  int h = (idx >> 5) & 15;
  int t = (idx >> 9) & 2047;
  int b = (idx >> 20) & 3;
  int which = idx >> 22;                        // 0=q, 1=k
  size_t base = ((size_t)(b*2048 + t))*3072 + (size_t)which*1024 + h*64 + i;
  float u1 = b2f(qkv[base]), u2 = b2f(qkv[base + 32]);
  float inv = exp2f(-(float)i * 0.4152410118609203f);  // 10000^(-i/32)
  float ang = (float)t * inv;
  float s, c;
  __sincosf(ang, &s, &c);
  qkv[base]      = f2b(u1*c - u2*s);
  qkv[base + 32] = f2b(u2*c + u1*s);
}

// ---------------- V [t][d] -> Vt [bh][d][t] bf16 ----------------
__global__ __launch_bounds__(256) void k_transpose_v(const uint16_t* __restrict__ qkv,
                                                     uint16_t* __restrict__ vt){
  __shared__ __align__(16) uint16_t tile[64*72];
  int bh = blockIdx.y;
  int t0 = blockIdx.x * 64;
  int b = bh >> 4, h = bh & 15;
  int r = threadIdx.x >> 2, ch = threadIdx.x & 3;
  const uint16_t* src = &qkv[((size_t)(b*2048 + t0 + r))*3072 + 2048 + h*64];
  *(uint4*)&tile[r*72 + ch*8]      = *(const uint4*)&src[ch*8];
  *(uint4*)&tile[r*72 + 32 + ch*8] = *(const uint4*)&src[32 + ch*8];
  __syncthreads();
  short8 v0, v1;
#pragma unroll
  for (int j = 0; j < 8; j++) v0[j] = (short)tile[(ch*8 + j)*72 + r];
#pragma unroll
  for (int j = 0; j < 8; j++) v1[j] = (short)tile[(32 + ch*8 + j)*72 + r];
  uint16_t* dst = &vt[((size_t)(bh*64 + r))*2048 + t0];
  *(short8*)&dst[ch*8]      = v0;
  *(short8*)&dst[32 + ch*8] = v1;
}

// ---------------- flash attention, block-cooperative LDS-staged K/V ----------------
// Grid: 1024 1-D blocks. Block -> (bh, X): XCD-chunked so each XCD (id%8) keeps
// 8 heads' K/V (4MB = its L2); X = 15-(i&15) so big-KT blocks dispatch first.
// Block owns q-rows [X*128, X*128+128): wave w owns 32 rows. All 4 waves sweep
// kt = 0..2X+1 together. Per tile: K[64 kpos][64 d] and Vt[64 d][64 kpos] staged
// into LDS by global_load_lds (16B/lane, linear dest), double-buffered, one
// barrier per tile (m97 structure). 16B-chunk XOR swizzle (chunk ^= row&7) applied
// on the GLOBAL source address (gload_lds dest must stay linear) and on the
// ds_read side -> conflict-free frag reads (was 16 lanes x stride 128B = same bank).
// Fixed-max softmax: p = exp(s/8 - 30), no running max; l reduced once at the end.
__global__ __launch_bounds__(256) void k_attn(const uint16_t* __restrict__ qkv,
                                              const uint16_t* __restrict__ vt,
                                              uint16_t* __restrict__ y){
  __shared__ __align__(16) uint16_t Klds[2][64*64];   // 16 KB
  __shared__ __align__(16) uint16_t Vlds[2][64*64];   // 16 KB
  __shared__ __align__(16) uint16_t Ps[4*32*72];      // 18 KB, wave-private P

  const int Did = blockIdx.x;
  const int g = Did & 7, ii = Did >> 3;
  const int bh = g*8 + (ii >> 4);               // 8 heads per XCD group
  const int X  = 15 - (ii & 15);                // long blocks first
  const int b = bh >> 4, h = bh & 15;
  const int lane = threadIdx.x & 63, w = threadIdx.x >> 6;
  const int quad = lane >> 4, l15 = lane & 15;
  const int swz = l15 & 7;
  uint16_t* Pw = &Ps[w*32*72];

  const uint16_t* Qbase  = qkv + (size_t)b*2048*3072 + h*64;
  const uint16_t* Kbase  = qkv + (size_t)b*2048*3072 + 1024 + h*64;
  const uint16_t* Vtbase = vt  + (size_t)bh*64*2048;
  const float M = 30.0f;                        // fixed softmax shift (cancels exactly)

  // staging role: waves 0,1 stage K rows 0-31/32-63; waves 2,3 stage Vt rows (d) 0-31/32-63
  const int isV  = w >> 1;
  const int rbase = (w & 1) * 32;
  const int rsub = lane >> 3, csub = lane & 7;

  // Q fragments: loaded once, live for the whole kernel
  const int qrow0 = X*128 + w*32;
  short8 aq[2][2];
#pragma unroll
  for (int mt = 0; mt < 2; mt++)
#pragma unroll
    for (int hf = 0; hf < 2; hf++)
      aq[mt][hf] = *(const short8*)&Qbase[(size_t)(qrow0 + mt*16 + l15)*3072 + hf*32 + quad*8];

  float4x o[2][4];
#pragma unroll
  for (int mt = 0; mt < 2; mt++) for (int nt = 0; nt < 4; nt++) o[mt][nt] = zero4();
  float lrow[2][4];
#pragma unroll
  for (int mt = 0; mt < 2; mt++) for (int rr = 0; rr < 4; rr++) lrow[mt][rr] = 0.f;

  const int KT = 2*X + 2;

  // prologue: stage tile 0 into buf 0 (source chunk pre-swizzled: lds stays linear)
#pragma unroll
  for (int j = 0; j < 4; j++){
    int r  = rbase + j*8 + rsub;
    int cg = csub ^ (r & 7);
    if (isV) gload16(Vtbase + (size_t)r*2048 + cg*8,          &Vlds[0][(rbase + j*8)*64 + lane*8]);
    else     gload16(Kbase  + (size_t)r*3072 + cg*8,          &Klds[0][(rbase + j*8)*64 + lane*8]);
  }

  int cur = 0;
  for (int kt = 0; kt < KT; ++kt){
    __syncthreads();                            // drains vmcnt -> buf[cur] staged; buf[cur^1] free
    if (kt + 1 < KT){
      int nb = cur ^ 1;
#pragma unroll
      for (int j = 0; j < 4; j++){
        int r  = rbase + j*8 + rsub;
        int cg = csub ^ (r & 7);
        if (isV) gload16(Vtbase + (size_t)r*2048 + (size_t)(kt+1)*64 + cg*8,
                         &Vlds[nb][(rbase + j*8)*64 + lane*8]);
        else     gload16(Kbase  + (size_t)((kt+1)*64 + r)*3072 + cg*8,
                         &Klds[nb][(rbase + j*8)*64 + lane*8]);
      }
    }

    // ---- QK^T from LDS (swizzled reads) ----
    float4x s[2][4];
#pragma unroll
    for (int mt = 0; mt < 2; mt++) for (int nt = 0; nt < 4; nt++) s[mt][nt] = zero4();
#pragma unroll
    for (int nt = 0; nt < 4; nt++){
      const uint16_t* krow = &Klds[cur][(nt*16 + l15)*64];
      short8 bk0 = *(const short8*)&krow[(quad ^ swz)*8];
      short8 bk1 = *(const short8*)&krow[((4 + quad) ^ swz)*8];
      s[0][nt] = __builtin_amdgcn_mfma_f32_16x16x32_bf16(aq[0][0], bk0, s[0][nt], 0, 0, 0);
      s[1][nt] = __builtin_amdgcn_mfma_f32_16x16x32_bf16(aq[1][0], bk0, s[1][nt], 0, 0, 0);
      s[0][nt] = __builtin_amdgcn_mfma_f32_16x16x32_bf16(aq[0][1], bk1, s[0][nt], 0, 0, 0);
      s[1][nt] = __builtin_amdgcn_mfma_f32_16x16x32_bf16(aq[1][1], bk1, s[1][nt], 0, 0, 0);
    }

    // causal mask: only the last two tiles (kt >= 2X) can cross the diagonal
    if (kt >= 2*X){
#pragma unroll
      for (int mt = 0; mt < 2; mt++)
#pragma unroll
        for (int nt = 0; nt < 4; nt++)
#pragma unroll
          for (int rr = 0; rr < 4; rr++){
            int tk = kt*64 + nt*16 + l15;
            int tq = qrow0 + mt*16 + quad*4 + rr;
            if (tk > tq) s[mt][nt][rr] = -1e30f;
          }
    }

    // p = exp(s*0.125 - M); accumulate row sums; P -> wave-private LDS (A-layout)
#pragma unroll
    for (int mt = 0; mt < 2; mt++)
#pragma unroll
      for (int nt = 0; nt < 4; nt++)
#pragma unroll
        for (int rr = 0; rr < 4; rr++){
          float pv = __expf(__builtin_fmaf(s[mt][nt][rr], 0.125f, -M));
          lrow[mt][rr] += pv;
          Pw[(mt*16 + quad*4 + rr)*72 + nt*16 + l15] = f2b(pv);
        }

    // ---- PV from LDS ----
    short8 ap[2][2];
#pragma unroll
    for (int mt = 0; mt < 2; mt++){
      ap[mt][0] = *(const short8*)&Pw[(mt*16 + l15)*72 + quad*8];
      ap[mt][1] = *(const short8*)&Pw[(mt*16 + l15)*72 + 32 + quad*8];
    }
#pragma unroll
    for (int nt = 0; nt < 4; nt++){
      const uint16_t* vrow = &Vlds[cur][(nt*16 + l15)*64];
      short8 bv0 = *(const short8*)&vrow[(quad ^ swz)*8];
      short8 bv1 = *(const short8*)&vrow[((4 + quad) ^ swz)*8];
      o[0][nt] = __builtin_amdgcn_mfma_f32_16x16x32_bf16(ap[0][0], bv0, o[0][nt], 0, 0, 0);
      o[1][nt] = __builtin_amdgcn_mfma_f32_16x16x32_bf16(ap[1][0], bv0, o[1][nt], 0, 0, 0);
      o[0][nt] = __builtin_amdgcn_mfma_f32_16x16x32_bf16(ap[0][1], bv1, o[0][nt], 0, 0, 0);
      o[1][nt] = __builtin_amdgcn_mfma_f32_16x16x32_bf16(ap[1][1], bv1, o[1][nt], 0, 0, 0);
    }
    cur ^= 1;
  }

  // epilogue: l reduction across the 16-lane dim, then normalized output
#pragma unroll
  for (int mt = 0; mt < 2; mt++)
#pragma unroll
    for (int rr = 0; rr < 4; rr++){
      float sm = lrow[mt][rr];
      for (int d = 1; d < 16; d <<= 1) sm += __shfl_xor(sm, d);
      float linv = 1.f / sm;
      int tq = qrow0 + mt*16 + quad*4 + rr;
      size_t rowbase = ((size_t)(b*2048 + tq))*1024 + h*64;
#pragma unroll
      for (int nt = 0; nt < 4; nt++)
        y[rowbase + nt*16 + l15] = f2b(o[mt][nt][rr] * linv);
    }
}

extern "C" void kernel_launch(void* const* d_in, const int* in_sizes, int n_in,
                              void* d_out, int out_size, void* d_ws, size_t ws_size,
                              hipStream_t stream){
  const float* x     = (const float*)d_in[0];
  const float* Wqkv  = (const float*)d_in[1];
  const float* bqkv  = (const float*)d_in[2];
  const float* Wproj = (const float*)d_in[3];
  const float* bproj = (const float*)d_in[4];

  uint16_t* p = (uint16_t*)d_ws;
  uint16_t* xb    = p; p += (size_t)8192*1024;   // x in bf16
  uint16_t* wqkvt = p; p += (size_t)3072*1024;   // W_qkv^T bf16
  uint16_t* wprjt = p; p += (size_t)1024*1024;   // W_proj^T bf16
  uint16_t* qkv   = p; p += (size_t)8192*3072;   // qkv (rope'd in place)
  uint16_t* vt    = p; p += (size_t)64*64*2048;  // V^T per head [bh][d][t]
  uint16_t* yb    = p; p += (size_t)8192*1024;   // attention output bf16

  k_f32_to_bf16<<<8192, 256, 0, stream>>>(x, xb, 2097152);
  k_transpose_bf16<<<dim3(96, 32), 256, 0, stream>>>(Wqkv, wqkvt, 1024, 3072);
  k_transpose_bf16<<<dim3(32, 32), 256, 0, stream>>>(Wproj, wprjt, 1024, 1024);
  k_gemm_bt<0><<<dim3(24, 64), 256, 0, stream>>>(xb, wqkvt, bqkv, (void*)qkv, 8192, 3072, 1024);
  k_rope<<<32768, 256, 0, stream>>>(qkv);
  k_transpose_v<<<dim3(32, 64), 256, 0, stream>>>(qkv, vt);
  k_attn<<<1024, 256, 0, stream>>>(qkv, vt, yb);
  k_gemm_bt<1><<<dim3(8, 64), 256, 0, stream>>>(yb, wprjt, bproj, d_out, 8192, 1024, 1024);
}

// Round 3
// 290.845 us; speedup vs baseline: 1.9527x; 1.0958x over previous
//
#include <hip/hip_runtime.h>
#include <cstdint>
#include <cstddef>

typedef __attribute__((ext_vector_type(8))) short short8;
typedef __attribute__((ext_vector_type(4))) float float4x;

__device__ __forceinline__ uint16_t f2b(float f){
  uint32_t u = __builtin_bit_cast(uint32_t, f);
  u += 0x7FFFu + ((u >> 16) & 1u);
  return (uint16_t)(u >> 16);
}
__device__ __forceinline__ float b2f(uint16_t h){
  uint32_t u = ((uint32_t)h) << 16;
  return __builtin_bit_cast(float, u);
}
__device__ __forceinline__ float4x zero4(){
  float4x v; v[0]=0.f; v[1]=0.f; v[2]=0.f; v[3]=0.f; return v;
}
// async global->LDS, 16B per lane. LDS dest = wave-uniform base + lane*16.
__device__ __forceinline__ void gload16(const uint16_t* g, uint16_t* l){
  __builtin_amdgcn_global_load_lds(
      (const __attribute__((address_space(1))) uint32_t*)g,
      (__attribute__((address_space(3))) uint32_t*)l, 16, 0, 0);
}

// ---------------- x (f32) -> bf16 ----------------
__global__ __launch_bounds__(256) void k_f32_to_bf16(const float* __restrict__ in,
                                                     uint16_t* __restrict__ out, int n4){
  int i = blockIdx.x * 256 + threadIdx.x;
  if (i < n4){
    float4 v = ((const float4*)in)[i];
    ushort4 o;
    o.x = f2b(v.x); o.y = f2b(v.y); o.z = f2b(v.z); o.w = f2b(v.w);
    ((ushort4*)out)[i] = o;
  }
}

// ---------------- W [K][N] f32 -> Wt [N][K] bf16 ----------------
__global__ __launch_bounds__(256) void k_transpose_bf16(const float* __restrict__ W,
                                                        uint16_t* __restrict__ Wt, int K, int N){
  __shared__ float tile[32][33];
  int k0 = blockIdx.y * 32, n0 = blockIdx.x * 32;
  int c = threadIdx.x & 31, r0 = threadIdx.x >> 5;
  for (int rr = r0; rr < 32; rr += 8)
    tile[rr][c] = W[(size_t)(k0 + rr) * N + n0 + c];
  __syncthreads();
  for (int rr = r0; rr < 32; rr += 8)
    Wt[(size_t)(n0 + rr) * K + k0 + c] = f2b(tile[c][rr]);
}

// ---------------- bf16 GEMM: C = A[m][k] * Bt[n][k] + bias, 128x128 tile ----------------
template<int OUTF>
__global__ __launch_bounds__(256, 3) void k_gemm_bt(const uint16_t* __restrict__ A,
                                                    const uint16_t* __restrict__ Bt,
                                                    const float* __restrict__ bias,
                                                    void* __restrict__ Cout,
                                                    int M, int N, int K){
  __shared__ __align__(16) uint16_t As[2][128*32];
  __shared__ __align__(16) uint16_t Bs[2][128*32];
  const int tid = threadIdx.x, lane = tid & 63, wave = tid >> 6;
  const int wr = wave >> 1, wc = wave & 1;
  const int m0 = blockIdx.y * 128, n0 = blockIdx.x * 128;
  const int quad = lane >> 4, l15 = lane & 15;
  const int rowA = tid >> 2, chA = tid & 3;

  float4x acc[4][4];
  for (int i = 0; i < 4; i++) for (int j = 0; j < 4; j++) acc[i][j] = zero4();

  const uint16_t* pa0 = &A[(size_t)(m0 + rowA)*K + chA*8];
  const uint16_t* pa1 = &A[(size_t)(m0 + rowA + 64)*K + chA*8];
  const uint16_t* pb0 = &Bt[(size_t)(n0 + rowA)*K + chA*8];
  const uint16_t* pb1 = &Bt[(size_t)(n0 + rowA + 64)*K + chA*8];

  gload16(pa0, &As[0][tid*8]);
  gload16(pa1, &As[0][64*32 + tid*8]);
  gload16(pb0, &Bs[0][tid*8]);
  gload16(pb1, &Bs[0][64*32 + tid*8]);

  int buf = 0;
  for (int k0 = 0; k0 < K; k0 += 32){
    __syncthreads();
    if (k0 + 32 < K){
      int nb = buf ^ 1;
      gload16(pa0 + k0 + 32, &As[nb][tid*8]);
      gload16(pa1 + k0 + 32, &As[nb][64*32 + tid*8]);
      gload16(pb0 + k0 + 32, &Bs[nb][tid*8]);
      gload16(pb1 + k0 + 32, &Bs[nb][64*32 + tid*8]);
    }
    short8 af[4], bf[4];
#pragma unroll
    for (int mt = 0; mt < 4; mt++)
      af[mt] = *(const short8*)&As[buf][(wr*64 + mt*16 + l15)*32 + quad*8];
#pragma unroll
    for (int nt = 0; nt < 4; nt++)
      bf[nt] = *(const short8*)&Bs[buf][(wc*64 + nt*16 + l15)*32 + quad*8];
#pragma unroll
    for (int mt = 0; mt < 4; mt++)
#pragma unroll
      for (int nt = 0; nt < 4; nt++)
        acc[mt][nt] = __builtin_amdgcn_mfma_f32_16x16x32_bf16(af[mt], bf[nt], acc[mt][nt], 0, 0, 0);
    buf ^= 1;
  }

#pragma unroll
  for (int mt = 0; mt < 4; mt++){
    int grow = m0 + wr*64 + mt*16 + quad*4;
#pragma unroll
    for (int nt = 0; nt < 4; nt++){
      int gcol = n0 + wc*64 + nt*16 + l15;
      float bv = bias[gcol];
#pragma unroll
      for (int r = 0; r < 4; r++){
        float v = acc[mt][nt][r] + bv;
        if (OUTF) ((float*)Cout)[(size_t)(grow + r)*N + gcol] = v;
        else      ((uint16_t*)Cout)[(size_t)(grow + r)*N + gcol] = f2b(v);
      }
    }
  }
}

// ---------------- RoPE in-place on q,k halves of qkv [BT][3072] bf16 ----------------
__global__ __launch_bounds__(256) void k_rope(uint16_t* __restrict__ qkv){
  int idx = blockIdx.x * 256 + threadIdx.x;     // 2^23 items
  int i = idx & 31;
  int h = (idx >> 5) & 15;
  int t = (idx >> 9) & 2047;
  int b = (idx >> 20) & 3;
  int which = idx >> 22;                        // 0=q, 1=k
  size_t base = ((size_t)(b*2048 + t))*3072 + (size_t)which*1024 + h*64 + i;
  float u1 = b2f(qkv[base]), u2 = b2f(qkv[base + 32]);
  float inv = exp2f(-(float)i * 0.4152410118609203f);  // 10000^(-i/32)
  float ang = (float)t * inv;
  float s, c;
  __sincosf(ang, &s, &c);
  qkv[base]      = f2b(u1*c - u2*s);
  qkv[base + 32] = f2b(u2*c + u1*s);
}

// ---------------- V [t][d] -> Vt [bh][d][t] bf16 ----------------
__global__ __launch_bounds__(256) void k_transpose_v(const uint16_t* __restrict__ qkv,
                                                     uint16_t* __restrict__ vt){
  __shared__ __align__(16) uint16_t tile[64*72];
  int bh = blockIdx.y;
  int t0 = blockIdx.x * 64;
  int b = bh >> 4, h = bh & 15;
  int r = threadIdx.x >> 2, ch = threadIdx.x & 3;
  const uint16_t* src = &qkv[((size_t)(b*2048 + t0 + r))*3072 + 2048 + h*64];
  *(uint4*)&tile[r*72 + ch*8]      = *(const uint4*)&src[ch*8];
  *(uint4*)&tile[r*72 + 32 + ch*8] = *(const uint4*)&src[32 + ch*8];
  __syncthreads();
  short8 v0, v1;
#pragma unroll
  for (int j = 0; j < 8; j++) v0[j] = (short)tile[(ch*8 + j)*72 + r];
#pragma unroll
  for (int j = 0; j < 8; j++) v1[j] = (short)tile[(32 + ch*8 + j)*72 + r];
  uint16_t* dst = &vt[((size_t)(bh*64 + r))*2048 + t0];
  *(short8*)&dst[ch*8]      = v0;
  *(short8*)&dst[32 + ch*8] = v1;
}

// ---------------- flash attention, balanced causal pairing ----------------
// Grid: 512 1-D blocks = 64 bh x 8 pairs -> EXACTLY 2 blocks/CU, all blocks
// identical work. Block (bh, X) processes q-chunks cA=X then cB=15-X (128 rows
// each, wave w owns 32). KT(c) = 2c+2 tiles -> KT_A+KT_B = 34 for every block.
// K/V tile addresses depend only on kt, and chunk B restarts at kt=0, so the
// block runs ONE flat 34-step loop: stage(next) -> barrier -> compute(cur),
// double-buffered; the chunk-A epilogue + Q reload fire at step KT_A (wave-
// uniform), overlapped with the already-issued prefetch. XCD-chunked mapping:
// Did&7 = XCD, 8 heads/XCD (K/V 4MB = its L2). 16B-chunk XOR swizzle on global
// source + ds_read side keeps gload_lds dest linear and frag reads conflict-free.
// Fixed-max softmax: p = exp(s/8 - 30), exact cancel; l reduced once per chunk.
__global__ __launch_bounds__(256) void k_attn(const uint16_t* __restrict__ qkv,
                                              const uint16_t* __restrict__ vt,
                                              uint16_t* __restrict__ y){
  __shared__ __align__(16) uint16_t Klds[2][64*64];   // 16 KB
  __shared__ __align__(16) uint16_t Vlds[2][64*64];   // 16 KB
  __shared__ __align__(16) uint16_t Ps[4*32*72];      // 18 KB, wave-private P

  const int Did = blockIdx.x;
  const int g = Did & 7, ii = Did >> 3;         // 64 blocks per XCD group
  const int bh = g*8 + (ii >> 3);               // 8 heads per XCD group
  const int X  = ii & 7;                        // pair index 0..7
  const int b = bh >> 4, h = bh & 15;
  const int lane = threadIdx.x & 63, w = threadIdx.x >> 6;
  const int quad = lane >> 4, l15 = lane & 15;
  const int swz = l15 & 7;
  uint16_t* Pw = &Ps[w*32*72];

  const uint16_t* Qbase  = qkv + (size_t)b*2048*3072 + h*64;
  const uint16_t* Kbase  = qkv + (size_t)b*2048*3072 + 1024 + h*64;
  const uint16_t* Vtbase = vt  + (size_t)bh*64*2048;
  const float M = 30.0f;                        // fixed softmax shift (cancels exactly)

  // staging role: waves 0,1 stage K rows 0-31/32-63; waves 2,3 stage Vt rows (d)
  const int isV  = w >> 1;
  const int rbase = (w & 1) * 32;
  const int rsub = lane >> 3, csub = lane & 7;

  const int cA = X, cB = 15 - X;
  const int KT_A = 2*cA + 2;
  const int TS = 34;                            // uniform total steps

  int c = cA;
  int qrow0 = c*128 + w*32;

  short8 aq[2][2];
#pragma unroll
  for (int mt = 0; mt < 2; mt++)
#pragma unroll
    for (int hf = 0; hf < 2; hf++)
      aq[mt][hf] = *(const short8*)&Qbase[(size_t)(qrow0 + mt*16 + l15)*3072 + hf*32 + quad*8];

  float4x o[2][4];
#pragma unroll
  for (int mt = 0; mt < 2; mt++) for (int nt = 0; nt < 4; nt++) o[mt][nt] = zero4();
  float lrow[2][4];
#pragma unroll
  for (int mt = 0; mt < 2; mt++) for (int rr = 0; rr < 4; rr++) lrow[mt][rr] = 0.f;

  // per-chunk epilogue: l-reduce across the 16-lane dim, normalize, store
  auto epilogue = [&](){
#pragma unroll
    for (int mt = 0; mt < 2; mt++)
#pragma unroll
      for (int rr = 0; rr < 4; rr++){
        float sm = lrow[mt][rr];
        for (int d = 1; d < 16; d <<= 1) sm += __shfl_xor(sm, d);
        float linv = 1.f / sm;
        int tq = qrow0 + mt*16 + quad*4 + rr;
        size_t rowbase = ((size_t)(b*2048 + tq))*1024 + h*64;
#pragma unroll
        for (int nt = 0; nt < 4; nt++)
          y[rowbase + nt*16 + l15] = f2b(o[mt][nt][rr] * linv);
      }
  };

  // prologue: stage tile kt=0 into buf 0 (source chunk pre-swizzled; LDS linear)
#pragma unroll
  for (int j = 0; j < 4; j++){
    int r  = rbase + j*8 + rsub;
    int cg = csub ^ (r & 7);
    if (isV) gload16(Vtbase + (size_t)r*2048 + cg*8, &Vlds[0][(rbase + j*8)*64 + lane*8]);
    else     gload16(Kbase  + (size_t)r*3072 + cg*8, &Klds[0][(rbase + j*8)*64 + lane*8]);
  }

  int cur = 0;
  for (int t = 0; t < TS; ++t){
    __syncthreads();                            // drains vmcnt -> buf[cur] staged
    const int kt = (t < KT_A) ? t : t - KT_A;
    if (t + 1 < TS){
      const int ktn = (t + 1 < KT_A) ? t + 1 : t + 1 - KT_A;  // crosses chunk boundary -> 0
      int nb = cur ^ 1;
#pragma unroll
      for (int j = 0; j < 4; j++){
        int r  = rbase + j*8 + rsub;
        int cg = csub ^ (r & 7);
        if (isV) gload16(Vtbase + (size_t)r*2048 + (size_t)ktn*64 + cg*8,
                         &Vlds[nb][(rbase + j*8)*64 + lane*8]);
        else     gload16(Kbase  + (size_t)(ktn*64 + r)*3072 + cg*8,
                         &Klds[nb][(rbase + j*8)*64 + lane*8]);
      }
    }

    if (t == KT_A){
      // chunk A done: emit it, switch to chunk B (wave-uniform branch)
      epilogue();
      c = cB; qrow0 = c*128 + w*32;
#pragma unroll
      for (int mt = 0; mt < 2; mt++)
#pragma unroll
        for (int hf = 0; hf < 2; hf++)
          aq[mt][hf] = *(const short8*)&Qbase[(size_t)(qrow0 + mt*16 + l15)*3072 + hf*32 + quad*8];
#pragma unroll
      for (int mt = 0; mt < 2; mt++) for (int nt = 0; nt < 4; nt++) o[mt][nt] = zero4();
#pragma unroll
      for (int mt = 0; mt < 2; mt++) for (int rr = 0; rr < 4; rr++) lrow[mt][rr] = 0.f;
    }

    // ---- QK^T from LDS (swizzled reads) ----
    float4x s[2][4];
#pragma unroll
    for (int mt = 0; mt < 2; mt++) for (int nt = 0; nt < 4; nt++) s[mt][nt] = zero4();
    __builtin_amdgcn_s_setprio(1);
#pragma unroll
    for (int nt = 0; nt < 4; nt++){
      const uint16_t* krow = &Klds[cur][(nt*16 + l15)*64];
      short8 bk0 = *(const short8*)&krow[(quad ^ swz)*8];
      short8 bk1 = *(const short8*)&krow[((4 + quad) ^ swz)*8];
      s[0][nt] = __builtin_amdgcn_mfma_f32_16x16x32_bf16(aq[0][0], bk0, s[0][nt], 0, 0, 0);
      s[1][nt] = __builtin_amdgcn_mfma_f32_16x16x32_bf16(aq[1][0], bk0, s[1][nt], 0, 0, 0);
      s[0][nt] = __builtin_amdgcn_mfma_f32_16x16x32_bf16(aq[0][1], bk1, s[0][nt], 0, 0, 0);
      s[1][nt] = __builtin_amdgcn_mfma_f32_16x16x32_bf16(aq[1][1], bk1, s[1][nt], 0, 0, 0);
    }
    __builtin_amdgcn_s_setprio(0);

    // causal mask: only the last two steps of each chunk cross the diagonal
    if (kt >= 2*c){
#pragma unroll
      for (int mt = 0; mt < 2; mt++)
#pragma unroll
        for (int nt = 0; nt < 4; nt++)
#pragma unroll
          for (int rr = 0; rr < 4; rr++){
            int tk = kt*64 + nt*16 + l15;
            int tq = qrow0 + mt*16 + quad*4 + rr;
            if (tk > tq) s[mt][nt][rr] = -1e30f;
          }
    }

    // p = exp(s*0.125 - M); accumulate row sums; P -> wave-private LDS (A-layout)
#pragma unroll
    for (int mt = 0; mt < 2; mt++)
#pragma unroll
      for (int nt = 0; nt < 4; nt++)
#pragma unroll
        for (int rr = 0; rr < 4; rr++){
          float pv = __expf(__builtin_fmaf(s[mt][nt][rr], 0.125f, -M));
          lrow[mt][rr] += pv;
          Pw[(mt*16 + quad*4 + rr)*72 + nt*16 + l15] = f2b(pv);
        }

    // ---- PV from LDS ----
    short8 ap[2][2];
#pragma unroll
    for (int mt = 0; mt < 2; mt++){
      ap[mt][0] = *(const short8*)&Pw[(mt*16 + l15)*72 + quad*8];
      ap[mt][1] = *(const short8*)&Pw[(mt*16 + l15)*72 + 32 + quad*8];
    }
    __builtin_amdgcn_s_setprio(1);
#pragma unroll
    for (int nt = 0; nt < 4; nt++){
      const uint16_t* vrow = &Vlds[cur][(nt*16 + l15)*64];
      short8 bv0 = *(const short8*)&vrow[(quad ^ swz)*8];
      short8 bv1 = *(const short8*)&vrow[((4 + quad) ^ swz)*8];
      o[0][nt] = __builtin_amdgcn_mfma_f32_16x16x32_bf16(ap[0][0], bv0, o[0][nt], 0, 0, 0);
      o[1][nt] = __builtin_amdgcn_mfma_f32_16x16x32_bf16(ap[1][0], bv0, o[1][nt], 0, 0, 0);
      o[0][nt] = __builtin_amdgcn_mfma_f32_16x16x32_bf16(ap[0][1], bv1, o[0][nt], 0, 0, 0);
      o[1][nt] = __builtin_amdgcn_mfma_f32_16x16x32_bf16(ap[1][1], bv1, o[1][nt], 0, 0, 0);
    }
    __builtin_amdgcn_s_setprio(0);
    cur ^= 1;
  }

  epilogue();                                   // chunk B
}

extern "C" void kernel_launch(void* const* d_in, const int* in_sizes, int n_in,
                              void* d_out, int out_size, void* d_ws, size_t ws_size,
                              hipStream_t stream){
  const float* x     = (const float*)d_in[0];
  const float* Wqkv  = (const float*)d_in[1];
  const float* bqkv  = (const float*)d_in[2];
  const float* Wproj = (const float*)d_in[3];
  const float* bproj = (const float*)d_in[4];

  uint16_t* p = (uint16_t*)d_ws;
  uint16_t* xb    = p; p += (size_t)8192*1024;   // x in bf16
  uint16_t* wqkvt = p; p += (size_t)3072*1024;   // W_qkv^T bf16
  uint16_t* wprjt = p; p += (size_t)1024*1024;   // W_proj^T bf16
  uint16_t* qkv   = p; p += (size_t)8192*3072;   // qkv (rope'd in place)
  uint16_t* vt    = p; p += (size_t)64*64*2048;  // V^T per head [bh][d][t]
  uint16_t* yb    = p; p += (size_t)8192*1024;   // attention output bf16

  k_f32_to_bf16<<<8192, 256, 0, stream>>>(x, xb, 2097152);
  k_transpose_bf16<<<dim3(96, 32), 256, 0, stream>>>(Wqkv, wqkvt, 1024, 3072);
  k_transpose_bf16<<<dim3(32, 32), 256, 0, stream>>>(Wproj, wprjt, 1024, 1024);
  k_gemm_bt<0><<<dim3(24, 64), 256, 0, stream>>>(xb, wqkvt, bqkv, (void*)qkv, 8192, 3072, 1024);
  k_rope<<<32768, 256, 0, stream>>>(qkv);
  k_transpose_v<<<dim3(32, 64), 256, 0, stream>>>(qkv, vt);
  k_attn<<<512, 256, 0, stream>>>(qkv, vt, yb);
  k_gemm_bt<1><<<dim3(8, 64), 256, 0, stream>>>(yb, wprjt, bproj, d_out, 8192, 1024, 1024);
}

// Round 4
// 283.189 us; speedup vs baseline: 2.0055x; 1.0270x over previous
//
#include <hip/hip_runtime.h>
#include <cstdint>
#include <cstddef>

typedef __attribute__((ext_vector_type(8))) short short8;
typedef __attribute__((ext_vector_type(4))) float float4x;
typedef __attribute__((ext_vector_type(16))) float float16x;
typedef __attribute__((ext_vector_type(2))) unsigned int uint2v;

__device__ __forceinline__ uint16_t f2b(float f){
  uint32_t u = __builtin_bit_cast(uint32_t, f);
  u += 0x7FFFu + ((u >> 16) & 1u);
  return (uint16_t)(u >> 16);
}
__device__ __forceinline__ float b2f(uint16_t h){
  uint32_t u = ((uint32_t)h) << 16;
  return __builtin_bit_cast(float, u);
}
__device__ __forceinline__ float4x zero4(){
  float4x v; v[0]=0.f; v[1]=0.f; v[2]=0.f; v[3]=0.f; return v;
}
__device__ __forceinline__ float16x zero16(){
  float16x v;
#pragma unroll
  for (int i = 0; i < 16; i++) v[i] = 0.f;
  return v;
}
// packed f32x2 -> bf16x2 (RNE), one instruction
__device__ __forceinline__ uint32_t cvtpk(float lo, float hi){
  uint32_t r;
  asm("v_cvt_pk_bf16_f32 %0, %1, %2" : "=v"(r) : "v"(lo), "v"(hi));
  return r;
}
// swap a[32:63] <-> b[0:31] (HK T12 recipe). Fallback: shfl_xor emulation.
__device__ __forceinline__ void plswap(uint32_t &a, uint32_t &b){
#if __has_builtin(__builtin_amdgcn_permlane32_swap)
  uint2v r = __builtin_amdgcn_permlane32_swap(a, b, false, false);
  a = r[0]; b = r[1];
#else
  uint32_t a2 = (uint32_t)__shfl_xor((int)a, 32, 64);
  uint32_t b2 = (uint32_t)__shfl_xor((int)b, 32, 64);
  bool lo = ((threadIdx.x & 63) < 32);
  uint32_t an = lo ? a : b2;
  uint32_t bn = lo ? a2 : b;
  a = an; b = bn;
#endif
}
__device__ __forceinline__ float fexp2(float x){
#if __has_builtin(__builtin_amdgcn_exp2f)
  return __builtin_amdgcn_exp2f(x);
#else
  return exp2f(x);
#endif
}
// async global->LDS, 16B per lane. LDS dest = wave-uniform base + lane*16.
__device__ __forceinline__ void gload16(const uint16_t* g, uint16_t* l){
  __builtin_amdgcn_global_load_lds(
      (const __attribute__((address_space(1))) uint32_t*)g,
      (__attribute__((address_space(3))) uint32_t*)l, 16, 0, 0);
}

// ---------------- x (f32) -> bf16 ----------------
__global__ __launch_bounds__(256) void k_f32_to_bf16(const float* __restrict__ in,
                                                     uint16_t* __restrict__ out, int n4){
  int i = blockIdx.x * 256 + threadIdx.x;
  if (i < n4){
    float4 v = ((const float4*)in)[i];
    ushort4 o;
    o.x = f2b(v.x); o.y = f2b(v.y); o.z = f2b(v.z); o.w = f2b(v.w);
    ((ushort4*)out)[i] = o;
  }
}

// ---------------- W [K][N] f32 -> Wt [N][K] bf16 ----------------
__global__ __launch_bounds__(256) void k_transpose_bf16(const float* __restrict__ W,
                                                        uint16_t* __restrict__ Wt, int K, int N){
  __shared__ float tile[32][33];
  int k0 = blockIdx.y * 32, n0 = blockIdx.x * 32;
  int c = threadIdx.x & 31, r0 = threadIdx.x >> 5;
  for (int rr = r0; rr < 32; rr += 8)
    tile[rr][c] = W[(size_t)(k0 + rr) * N + n0 + c];
  __syncthreads();
  for (int rr = r0; rr < 32; rr += 8)
    Wt[(size_t)(n0 + rr) * K + k0 + c] = f2b(tile[c][rr]);
}

// ---------------- bf16 GEMM: C = A[m][k] * Bt[n][k] + bias, 128x128 tile ----------------
template<int OUTF>
__global__ __launch_bounds__(256, 3) void k_gemm_bt(const uint16_t* __restrict__ A,
                                                    const uint16_t* __restrict__ Bt,
                                                    const float* __restrict__ bias,
                                                    void* __restrict__ Cout,
                                                    int M, int N, int K){
  __shared__ __align__(16) uint16_t As[2][128*32];
  __shared__ __align__(16) uint16_t Bs[2][128*32];
  const int tid = threadIdx.x, lane = tid & 63, wave = tid >> 6;
  const int wr = wave >> 1, wc = wave & 1;
  const int m0 = blockIdx.y * 128, n0 = blockIdx.x * 128;
  const int quad = lane >> 4, l15 = lane & 15;
  const int rowA = tid >> 2, chA = tid & 3;

  float4x acc[4][4];
  for (int i = 0; i < 4; i++) for (int j = 0; j < 4; j++) acc[i][j] = zero4();

  const uint16_t* pa0 = &A[(size_t)(m0 + rowA)*K + chA*8];
  const uint16_t* pa1 = &A[(size_t)(m0 + rowA + 64)*K + chA*8];
  const uint16_t* pb0 = &Bt[(size_t)(n0 + rowA)*K + chA*8];
  const uint16_t* pb1 = &Bt[(size_t)(n0 + rowA + 64)*K + chA*8];

  gload16(pa0, &As[0][tid*8]);
  gload16(pa1, &As[0][64*32 + tid*8]);
  gload16(pb0, &Bs[0][tid*8]);
  gload16(pb1, &Bs[0][64*32 + tid*8]);

  int buf = 0;
  for (int k0 = 0; k0 < K; k0 += 32){
    __syncthreads();
    if (k0 + 32 < K){
      int nb = buf ^ 1;
      gload16(pa0 + k0 + 32, &As[nb][tid*8]);
      gload16(pa1 + k0 + 32, &As[nb][64*32 + tid*8]);
      gload16(pb0 + k0 + 32, &Bs[nb][tid*8]);
      gload16(pb1 + k0 + 32, &Bs[nb][64*32 + tid*8]);
    }
    short8 af[4], bf[4];
#pragma unroll
    for (int mt = 0; mt < 4; mt++)
      af[mt] = *(const short8*)&As[buf][(wr*64 + mt*16 + l15)*32 + quad*8];
#pragma unroll
    for (int nt = 0; nt < 4; nt++)
      bf[nt] = *(const short8*)&Bs[buf][(wc*64 + nt*16 + l15)*32 + quad*8];
#pragma unroll
    for (int mt = 0; mt < 4; mt++)
#pragma unroll
      for (int nt = 0; nt < 4; nt++)
        acc[mt][nt] = __builtin_amdgcn_mfma_f32_16x16x32_bf16(af[mt], bf[nt], acc[mt][nt], 0, 0, 0);
    buf ^= 1;
  }

#pragma unroll
  for (int mt = 0; mt < 4; mt++){
    int grow = m0 + wr*64 + mt*16 + quad*4;
#pragma unroll
    for (int nt = 0; nt < 4; nt++){
      int gcol = n0 + wc*64 + nt*16 + l15;
      float bv = bias[gcol];
#pragma unroll
      for (int r = 0; r < 4; r++){
        float v = acc[mt][nt][r] + bv;
        if (OUTF) ((float*)Cout)[(size_t)(grow + r)*N + gcol] = v;
        else      ((uint16_t*)Cout)[(size_t)(grow + r)*N + gcol] = f2b(v);
      }
    }
  }
}

// ---------------- RoPE in-place on q,k halves of qkv [BT][3072] bf16 ----------------
__global__ __launch_bounds__(256) void k_rope(uint16_t* __restrict__ qkv){
  int idx = blockIdx.x * 256 + threadIdx.x;     // 2^23 items
  int i = idx & 31;
  int h = (idx >> 5) & 15;
  int t = (idx >> 9) & 2047;
  int b = (idx >> 20) & 3;
  int which = idx >> 22;                        // 0=q, 1=k
  size_t base = ((size_t)(b*2048 + t))*3072 + (size_t)which*1024 + h*64 + i;
  float u1 = b2f(qkv[base]), u2 = b2f(qkv[base + 32]);
  float inv = exp2f(-(float)i * 0.4152410118609203f);  // 10000^(-i/32)
  float ang = (float)t * inv;
  float s, c;
  __sincosf(ang, &s, &c);
  qkv[base]      = f2b(u1*c - u2*s);
  qkv[base + 32] = f2b(u2*c + u1*s);
}

// ---------------- V [t][d] -> Vt [bh][d][t] bf16 ----------------
__global__ __launch_bounds__(256) void k_transpose_v(const uint16_t* __restrict__ qkv,
                                                     uint16_t* __restrict__ vt){
  __shared__ __align__(16) uint16_t tile[64*72];
  int bh = blockIdx.y;
  int t0 = blockIdx.x * 64;
  int b = bh >> 4, h = bh & 15;
  int r = threadIdx.x >> 2, ch = threadIdx.x & 3;
  const uint16_t* src = &qkv[((size_t)(b*2048 + t0 + r))*3072 + 2048 + h*64];
  *(uint4*)&tile[r*72 + ch*8]      = *(const uint4*)&src[ch*8];
  *(uint4*)&tile[r*72 + 32 + ch*8] = *(const uint4*)&src[32 + ch*8];
  __syncthreads();
  short8 v0, v1;
#pragma unroll
  for (int j = 0; j < 8; j++) v0[j] = (short)tile[(ch*8 + j)*72 + r];
#pragma unroll
  for (int j = 0; j < 8; j++) v1[j] = (short)tile[(32 + ch*8 + j)*72 + r];
  uint16_t* dst = &vt[((size_t)(bh*64 + r))*2048 + t0];
  *(short8*)&dst[ch*8]      = v0;
  *(short8*)&dst[32 + ch*8] = v1;
}

// ---------------- flash attention: 32x32 swapped QK^T, in-register P ----------------
// Grid 512 = 64 bh x 8 pairs, balanced (34 tiles/block), XCD-chunked (Did&7=XCD).
// Wave w owns 32 q-rows. Swapped QK^T: S^T = mfma32(K_frag, Q_frag) puts each
// lane's P-slice lane-local (q = lane&31, 32 k-values in regs). Softmax fully
// in-register: exp2(fma) + lane-local row sums (no shfl tree, no P-LDS).
// P -> PV A-frags via v_cvt_pk_bf16_f32 pairs + permlane32_swap (HK T12 recipe):
// per K16-chunk kc: regs R..R+3 (R = 8*(kc&1)+4*hi) packed, halves swapped.
// K/V staged to LDS by global_load_lds (double-buffered, one barrier/tile,
// 16B-chunk XOR swizzle on global source + read side). LDS = 32 KB (P buffer gone).
__global__ __launch_bounds__(256) void k_attn(const uint16_t* __restrict__ qkv,
                                              const uint16_t* __restrict__ vt,
                                              uint16_t* __restrict__ y){
  __shared__ __align__(16) uint16_t Klds[2][64*64];   // 16 KB
  __shared__ __align__(16) uint16_t Vlds[2][64*64];   // 16 KB

  const int Did = blockIdx.x;
  const int g = Did & 7, ii = Did >> 3;         // 64 blocks per XCD group
  const int bh = g*8 + (ii >> 3);               // 8 heads per XCD group
  const int X  = ii & 7;                        // pair index 0..7
  const int b = bh >> 4, h = bh & 15;
  const int lane = threadIdx.x & 63, w = threadIdx.x >> 6;
  const int l31 = lane & 31, hi = lane >> 5;

  const uint16_t* Qbase  = qkv + (size_t)b*2048*3072 + h*64;
  const uint16_t* Kbase  = qkv + (size_t)b*2048*3072 + 1024 + h*64;
  const uint16_t* Vtbase = vt  + (size_t)bh*64*2048;

  // softmax scale folded to base-2: p = 2^(s*S2 - M2); fixed shift cancels in l
  const float S2 = 0.18033688011112042f;        // 0.125 * log2(e)
  const float M2 = 43.28085122666890f;          // 30 * log2(e)

  // staging role: waves 0,1 stage K rows 0-31/32-63; waves 2,3 stage Vt rows (d)
  const int isV  = w >> 1;
  const int rbase = (w & 1) * 32;
  const int rsub = lane >> 3, csub = lane & 7;

  const int cA = X, cB = 15 - X;
  const int KT_A = 2*cA + 2;
  const int TS = 34;                            // uniform total steps

  int c = cA;
  int qr = c*128 + w*32;                        // wave's q-row base

  // Q B-frags (col=q=l31, k-elems d = kc*16 + hi*8 + j), live for the chunk
  short8 aq[4];
#pragma unroll
  for (int kc = 0; kc < 4; kc++)
    aq[kc] = *(const short8*)&Qbase[(size_t)(qr + l31)*3072 + kc*16 + hi*8];

  float16x o[2];
  o[0] = zero16(); o[1] = zero16();
  float lr4[4] = {0.f, 0.f, 0.f, 0.f};

  // per-chunk epilogue: combine halves' row sums, normalize, store
  auto epilogue = [&](){
    float l = (lr4[0] + lr4[1]) + (lr4[2] + lr4[3]);
    l += __shfl_xor(l, 32, 64);                 // full row sum for q = l31
    float linv = 1.f / l;
    float lv[16];
#pragma unroll
    for (int r = 0; r < 16; r++)
      lv[r] = __shfl(linv, (r&3) + 8*(r>>2) + 4*hi, 64);
#pragma unroll
    for (int dt = 0; dt < 2; dt++)
#pragma unroll
      for (int r = 0; r < 16; r++){
        int row = (r&3) + 8*(r>>2) + 4*hi;
        y[((size_t)(b*2048 + qr + row))*1024 + h*64 + dt*32 + l31] = f2b(o[dt][r] * lv[r]);
      }
  };

  // prologue: stage tile kt=0 into buf 0 (source chunk pre-swizzled; LDS linear)
#pragma unroll
  for (int j = 0; j < 4; j++){
    int r  = rbase + j*8 + rsub;
    int cg = csub ^ (r & 7);
    if (isV) gload16(Vtbase + (size_t)r*2048 + cg*8, &Vlds[0][(rbase + j*8)*64 + lane*8]);
    else     gload16(Kbase  + (size_t)r*3072 + cg*8, &Klds[0][(rbase + j*8)*64 + lane*8]);
  }

  int cur = 0;
  for (int t = 0; t < TS; ++t){
    __syncthreads();                            // buf[cur] staged; buf[cur^1] free
    const int kt = (t < KT_A) ? t : t - KT_A;
    if (t + 1 < TS){
      const int ktn = (t + 1 < KT_A) ? t + 1 : t + 1 - KT_A;  // chunk boundary -> 0
      int nb = cur ^ 1;
#pragma unroll
      for (int j = 0; j < 4; j++){
        int r  = rbase + j*8 + rsub;
        int cg = csub ^ (r & 7);
        if (isV) gload16(Vtbase + (size_t)r*2048 + (size_t)ktn*64 + cg*8,
                         &Vlds[nb][(rbase + j*8)*64 + lane*8]);
        else     gload16(Kbase  + (size_t)(ktn*64 + r)*3072 + cg*8,
                         &Klds[nb][(rbase + j*8)*64 + lane*8]);
      }
    }

    if (t == KT_A){
      // chunk A done: emit it, switch to chunk B (wave-uniform branch)
      epilogue();
      c = cB; qr = c*128 + w*32;
#pragma unroll
      for (int kc = 0; kc < 4; kc++)
        aq[kc] = *(const short8*)&Qbase[(size_t)(qr + l31)*3072 + kc*16 + hi*8];
      o[0] = zero16(); o[1] = zero16();
      lr4[0] = lr4[1] = lr4[2] = lr4[3] = 0.f;
    }

    // ---- swapped QK^T: S^T[kpos][q] (p0: kpos 0-31, p1: 32-63) ----
    float16x p0 = zero16(), p1 = zero16();
    __builtin_amdgcn_s_setprio(1);
#pragma unroll
    for (int kc = 0; kc < 4; kc++){
      const int ch = 2*kc + hi;
      short8 ak0 = *(const short8*)&Klds[cur][(l31)*64      + ((ch ^ (l31 & 7))*8)];
      short8 ak1 = *(const short8*)&Klds[cur][(32 + l31)*64 + ((ch ^ (l31 & 7))*8)];
      p0 = __builtin_amdgcn_mfma_f32_32x32x16_bf16(ak0, aq[kc], p0, 0, 0, 0);
      p1 = __builtin_amdgcn_mfma_f32_32x32x16_bf16(ak1, aq[kc], p1, 0, 0, 0);
    }
    __builtin_amdgcn_s_setprio(0);

    // causal mask: only the last two steps of each chunk cross the diagonal
    if (kt >= 2*c){
      const int tq = qr + l31;
#pragma unroll
      for (int r = 0; r < 16; r++){
        int kb = kt*64 + (r&3) + 8*(r>>2) + 4*hi;
        if (kb > tq)      p0[r] = -1e30f;
        if (kb + 32 > tq) p1[r] = -1e30f;
      }
    }

    // softmax: p = exp2(s*S2 - M2), lane-local row sums
#pragma unroll
    for (int r = 0; r < 16; r++){
      float e0 = fexp2(__builtin_fmaf(p0[r], S2, -M2));
      float e1 = fexp2(__builtin_fmaf(p1[r], S2, -M2));
      lr4[r & 3] += e0 + e1;
      p0[r] = e0; p1[r] = e1;
    }

    // ---- PV: per K16-chunk build A-frag in-register (cvt_pk + permlane32_swap) ----
    __builtin_amdgcn_s_setprio(1);
#pragma unroll
    for (int kc = 0; kc < 4; kc++){
      const int e8 = (kc & 1)*8;
      uint32_t w0, w1, w2, w3;
      if (kc < 2){
        w0 = cvtpk(p0[e8+0], p0[e8+1]); w1 = cvtpk(p0[e8+2], p0[e8+3]);
        w2 = cvtpk(p0[e8+4], p0[e8+5]); w3 = cvtpk(p0[e8+6], p0[e8+7]);
      } else {
        w0 = cvtpk(p1[e8+0], p1[e8+1]); w1 = cvtpk(p1[e8+2], p1[e8+3]);
        w2 = cvtpk(p1[e8+4], p1[e8+5]); w3 = cvtpk(p1[e8+6], p1[e8+7]);
      }
      plswap(w0, w2);                           // (w0,w2): halves exchanged
      plswap(w1, w3);
      union { uint32_t u[4]; short8 s; } ap;
      ap.u[0] = w0; ap.u[1] = w1; ap.u[2] = w2; ap.u[3] = w3;

      const int ch = 2*kc + hi;
      short8 bv0 = *(const short8*)&Vlds[cur][(l31)*64      + ((ch ^ (l31 & 7))*8)];
      short8 bv1 = *(const short8*)&Vlds[cur][(32 + l31)*64 + ((ch ^ (l31 & 7))*8)];
      o[0] = __builtin_amdgcn_mfma_f32_32x32x16_bf16(ap.s, bv0, o[0], 0, 0, 0);
      o[1] = __builtin_amdgcn_mfma_f32_32x32x16_bf16(ap.s, bv1, o[1], 0, 0, 0);
    }
    __builtin_amdgcn_s_setprio(0);
    cur ^= 1;
  }

  epilogue();                                   // chunk B
}

extern "C" void kernel_launch(void* const* d_in, const int* in_sizes, int n_in,
                              void* d_out, int out_size, void* d_ws, size_t ws_size,
                              hipStream_t stream){
  const float* x     = (const float*)d_in[0];
  const float* Wqkv  = (const float*)d_in[1];
  const float* bqkv  = (const float*)d_in[2];
  const float* Wproj = (const float*)d_in[3];
  const float* bproj = (const float*)d_in[4];

  uint16_t* p = (uint16_t*)d_ws;
  uint16_t* xb    = p; p += (size_t)8192*1024;   // x in bf16
  uint16_t* wqkvt = p; p += (size_t)3072*1024;   // W_qkv^T bf16
  uint16_t* wprjt = p; p += (size_t)1024*1024;   // W_proj^T bf16
  uint16_t* qkv   = p; p += (size_t)8192*3072;   // qkv (rope'd in place)
  uint16_t* vt    = p; p += (size_t)64*64*2048;  // V^T per head [bh][d][t]
  uint16_t* yb    = p; p += (size_t)8192*1024;   // attention output bf16

  k_f32_to_bf16<<<8192, 256, 0, stream>>>(x, xb, 2097152);
  k_transpose_bf16<<<dim3(96, 32), 256, 0, stream>>>(Wqkv, wqkvt, 1024, 3072);
  k_transpose_bf16<<<dim3(32, 32), 256, 0, stream>>>(Wproj, wprjt, 1024, 1024);
  k_gemm_bt<0><<<dim3(24, 64), 256, 0, stream>>>(xb, wqkvt, bqkv, (void*)qkv, 8192, 3072, 1024);
  k_rope<<<32768, 256, 0, stream>>>(qkv);
  k_transpose_v<<<dim3(32, 64), 256, 0, stream>>>(qkv, vt);
  k_attn<<<512, 256, 0, stream>>>(qkv, vt, yb);
  k_gemm_bt<1><<<dim3(8, 64), 256, 0, stream>>>(yb, wprjt, bproj, d_out, 8192, 1024, 1024);
}

// Round 6
// 261.543 us; speedup vs baseline: 2.1715x; 1.0828x over previous
//
#include <hip/hip_runtime.h>
#include <cstdint>
#include <cstddef>

typedef __attribute__((ext_vector_type(8))) short short8;
typedef __attribute__((ext_vector_type(4))) float float4x;
typedef __attribute__((ext_vector_type(16))) float float16x;
typedef __attribute__((ext_vector_type(2))) unsigned int uint2v;

__device__ __forceinline__ uint16_t f2b(float f){
  uint32_t u = __builtin_bit_cast(uint32_t, f);
  u += 0x7FFFu + ((u >> 16) & 1u);
  return (uint16_t)(u >> 16);
}
__device__ __forceinline__ float b2f(uint16_t h){
  uint32_t u = ((uint32_t)h) << 16;
  return __builtin_bit_cast(float, u);
}
__device__ __forceinline__ float4x zero4(){
  float4x v; v[0]=0.f; v[1]=0.f; v[2]=0.f; v[3]=0.f; return v;
}
__device__ __forceinline__ float16x zero16(){
  float16x v;
#pragma unroll
  for (int i = 0; i < 16; i++) v[i] = 0.f;
  return v;
}
// packed f32x2 -> bf16x2 (RNE), one instruction
__device__ __forceinline__ uint32_t cvtpk(float lo, float hi){
  uint32_t r;
  asm("v_cvt_pk_bf16_f32 %0, %1, %2" : "=v"(r) : "v"(lo), "v"(hi));
  return r;
}
// swap a[32:63] <-> b[0:31] (HK T12 recipe). Fallback: shfl_xor emulation.
__device__ __forceinline__ void plswap(uint32_t &a, uint32_t &b){
#if __has_builtin(__builtin_amdgcn_permlane32_swap)
  uint2v r = __builtin_amdgcn_permlane32_swap(a, b, false, false);
  a = r[0]; b = r[1];
#else
  uint32_t a2 = (uint32_t)__shfl_xor((int)a, 32, 64);
  uint32_t b2 = (uint32_t)__shfl_xor((int)b, 32, 64);
  bool lo = ((threadIdx.x & 63) < 32);
  uint32_t an = lo ? a : b2;
  uint32_t bn = lo ? a2 : b;
  a = an; b = bn;
#endif
}
__device__ __forceinline__ float fexp2(float x){
#if __has_builtin(__builtin_amdgcn_exp2f)
  return __builtin_amdgcn_exp2f(x);
#else
  return exp2f(x);
#endif
}
// async global->LDS, 16B per lane. LDS dest = wave-uniform base + lane*16.
__device__ __forceinline__ void gload16(const uint16_t* g, uint16_t* l){
  __builtin_amdgcn_global_load_lds(
      (const __attribute__((address_space(1))) uint32_t*)g,
      (__attribute__((address_space(3))) uint32_t*)l, 16, 0, 0);
}

// ---------------- x (f32) -> bf16 ----------------
__global__ __launch_bounds__(256) void k_f32_to_bf16(const float* __restrict__ in,
                                                     uint16_t* __restrict__ out, int n4){
  int i = blockIdx.x * 256 + threadIdx.x;
  if (i < n4){
    float4 v = ((const float4*)in)[i];
    ushort4 o;
    o.x = f2b(v.x); o.y = f2b(v.y); o.z = f2b(v.z); o.w = f2b(v.w);
    ((ushort4*)out)[i] = o;
  }
}

// ---------------- W [K][N] f32 -> Wt [N][K] bf16 ----------------
__global__ __launch_bounds__(256) void k_transpose_bf16(const float* __restrict__ W,
                                                        uint16_t* __restrict__ Wt, int K, int N){
  __shared__ float tile[32][33];
  int k0 = blockIdx.y * 32, n0 = blockIdx.x * 32;
  int c = threadIdx.x & 31, r0 = threadIdx.x >> 5;
  for (int rr = r0; rr < 32; rr += 8)
    tile[rr][c] = W[(size_t)(k0 + rr) * N + n0 + c];
  __syncthreads();
  for (int rr = r0; rr < 32; rr += 8)
    Wt[(size_t)(n0 + rr) * K + k0 + c] = f2b(tile[c][rr]);
}

// ---------------- fused QKV GEMM: qkv = x*Wqkv + b, RoPE(q,k) in-epilogue,
// ---------------- V written directly transposed to vt [bh][d][t] ----------------
// 128x128 tile, m97 2-phase structure. Epilogue:
//  - blocks with n0 < 2048 (q,k): rope pairs (i, i+32) are acc[mt][nt] /
//    acc[mt][nt+2] in the SAME thread (wave spans exactly one 64-col head);
//    rotate in f32, round once, write to qkv.
//  - blocks with n0 >= 2048 (v): per-wave 64x64 in-LDS transpose.
//    Tile is [64 d][72] (stride 72 entries = 144 B, 16B-aligned) -- r5 bug was
//    stride 40 with t-index up to 63 (row overlap -> garbage V). Per-wave region
//    4608 entries, 4 waves = 18432 entries (36 KB); taken AFTER the block-uniform
//    barrier, when As/Bs (first 16384 entries) are dead.
__global__ __launch_bounds__(256, 3) void k_gemm_qkv(const uint16_t* __restrict__ A,
                                                     const uint16_t* __restrict__ Bt,
                                                     const float* __restrict__ bias,
                                                     uint16_t* __restrict__ qkv,
                                                     uint16_t* __restrict__ vt){
  const int K = 1024;
  __shared__ __align__(16) uint16_t SM[18432];        // As:[0,8192) Bs:[8192,16384); T: per-wave 4608
  uint16_t* As_ = SM;
  uint16_t* Bs_ = SM + 8192;
  const int tid = threadIdx.x, lane = tid & 63, wave = tid >> 6;
  const int wr = wave >> 1, wc = wave & 1;
  const int m0 = blockIdx.y * 128, n0 = blockIdx.x * 128;
  const int quad = lane >> 4, l15 = lane & 15;
  const int rowA = tid >> 2, chA = tid & 3;

  float4x acc[4][4];
  for (int i = 0; i < 4; i++) for (int j = 0; j < 4; j++) acc[i][j] = zero4();

  const uint16_t* pa0 = &A[(size_t)(m0 + rowA)*K + chA*8];
  const uint16_t* pa1 = &A[(size_t)(m0 + rowA + 64)*K + chA*8];
  const uint16_t* pb0 = &Bt[(size_t)(n0 + rowA)*K + chA*8];
  const uint16_t* pb1 = &Bt[(size_t)(n0 + rowA + 64)*K + chA*8];

  gload16(pa0, &As_[tid*8]);
  gload16(pa1, &As_[64*32 + tid*8]);
  gload16(pb0, &Bs_[tid*8]);
  gload16(pb1, &Bs_[64*32 + tid*8]);

  int buf = 0;
  for (int k0 = 0; k0 < K; k0 += 32){
    __syncthreads();
    if (k0 + 32 < K){
      int nb = buf ^ 1;
      gload16(pa0 + k0 + 32, &As_[nb*4096 + tid*8]);
      gload16(pa1 + k0 + 32, &As_[nb*4096 + 64*32 + tid*8]);
      gload16(pb0 + k0 + 32, &Bs_[nb*4096 + tid*8]);
      gload16(pb1 + k0 + 32, &Bs_[nb*4096 + 64*32 + tid*8]);
    }
    short8 af[4], bfr[4];
#pragma unroll
    for (int mt = 0; mt < 4; mt++)
      af[mt] = *(const short8*)&As_[buf*4096 + (wr*64 + mt*16 + l15)*32 + quad*8];
#pragma unroll
    for (int nt = 0; nt < 4; nt++)
      bfr[nt] = *(const short8*)&Bs_[buf*4096 + (wc*64 + nt*16 + l15)*32 + quad*8];
#pragma unroll
    for (int mt = 0; mt < 4; mt++)
#pragma unroll
      for (int nt = 0; nt < 4; nt++)
        acc[mt][nt] = __builtin_amdgcn_mfma_f32_16x16x32_bf16(af[mt], bfr[nt], acc[mt][nt], 0, 0, 0);
    buf ^= 1;
  }

  if (blockIdx.x < 16){
    // ---- q,k halves: bias + RoPE in-register, write to qkv ----
#pragma unroll
    for (int mt = 0; mt < 4; mt++){
      int grow = m0 + wr*64 + mt*16 + quad*4;
      int tpos = grow & 2047;                    // batch-local position
#pragma unroll
      for (int nt = 0; nt < 2; nt++){
        int gcol = n0 + wc*64 + nt*16 + l15;
        float bv1 = bias[gcol], bv2 = bias[gcol + 32];
        int i = nt*16 + l15;                     // head-local index 0..31
        float inv = exp2f(-(float)i * 0.4152410118609203f);  // 10000^(-i/32)
#pragma unroll
        for (int r = 0; r < 4; r++){
          float ang = (float)(tpos + r) * inv;
          float s, c;
          __sincosf(ang, &s, &c);
          float u1 = acc[mt][nt][r]   + bv1;
          float u2 = acc[mt][nt+2][r] + bv2;
          qkv[(size_t)(grow + r)*3072 + gcol]      = f2b(u1*c - u2*s);
          qkv[(size_t)(grow + r)*3072 + gcol + 32] = f2b(u2*c + u1*s);
        }
      }
    }
  } else {
    // ---- v half: bias, transpose 64x64 per wave through LDS, write vt[d][t] ----
    __syncthreads();                             // all waves done reading As/Bs
    uint16_t* T = &SM[wave*4608];                // [64 d][72] (stride 144 B)
#pragma unroll
    for (int mt = 0; mt < 4; mt++)
#pragma unroll
      for (int nt = 0; nt < 4; nt++){
        int gcol = n0 + wc*64 + nt*16 + l15;
        float bv = bias[gcol];
#pragma unroll
        for (int r = 0; r < 4; r++)
          T[(nt*16 + l15)*72 + mt*16 + quad*4 + r] = f2b(acc[mt][nt][r] + bv);
      }
    __syncthreads();                             // writes visible (block-uniform barrier)
    const int h = (n0 + wc*64 - 2048) >> 6;
    const int tg0 = m0 + wr*64;
    const int bb = tg0 >> 11, tb = tg0 & 2047;
    const int bh64 = (bb*16 + h)*64;
    const int d32 = lane & 31, th = lane >> 5;
#pragma unroll
    for (int dd = 0; dd < 2; dd++)
#pragma unroll
      for (int it = 0; it < 4; it++){
        short8 v = *(const short8*)&T[(d32 + 32*dd)*72 + th*32 + it*8];
        *(short8*)&vt[((size_t)(bh64 + d32 + 32*dd))*2048 + tb + th*32 + it*8] = v;
      }
  }
}

// ---------------- bf16 GEMM: C = A[m][k] * Bt[n][k] + bias (f32 out), 128x128 tile ----------------
__global__ __launch_bounds__(256, 3) void k_gemm_proj(const uint16_t* __restrict__ A,
                                                      const uint16_t* __restrict__ Bt,
                                                      const float* __restrict__ bias,
                                                      float* __restrict__ Cout,
                                                      int M, int N, int K){
  __shared__ __align__(16) uint16_t As[2][128*32];
  __shared__ __align__(16) uint16_t Bs[2][128*32];
  const int tid = threadIdx.x, lane = tid & 63, wave = tid >> 6;
  const int wr = wave >> 1, wc = wave & 1;
  const int m0 = blockIdx.y * 128, n0 = blockIdx.x * 128;
  const int quad = lane >> 4, l15 = lane & 15;
  const int rowA = tid >> 2, chA = tid & 3;

  float4x acc[4][4];
  for (int i = 0; i < 4; i++) for (int j = 0; j < 4; j++) acc[i][j] = zero4();

  const uint16_t* pa0 = &A[(size_t)(m0 + rowA)*K + chA*8];
  const uint16_t* pa1 = &A[(size_t)(m0 + rowA + 64)*K + chA*8];
  const uint16_t* pb0 = &Bt[(size_t)(n0 + rowA)*K + chA*8];
  const uint16_t* pb1 = &Bt[(size_t)(n0 + rowA + 64)*K + chA*8];

  gload16(pa0, &As[0][tid*8]);
  gload16(pa1, &As[0][64*32 + tid*8]);
  gload16(pb0, &Bs[0][tid*8]);
  gload16(pb1, &Bs[0][64*32 + tid*8]);

  int buf = 0;
  for (int k0 = 0; k0 < K; k0 += 32){
    __syncthreads();
    if (k0 + 32 < K){
      int nb = buf ^ 1;
      gload16(pa0 + k0 + 32, &As[nb][tid*8]);
      gload16(pa1 + k0 + 32, &As[nb][64*32 + tid*8]);
      gload16(pb0 + k0 + 32, &Bs[nb][tid*8]);
      gload16(pb1 + k0 + 32, &Bs[nb][64*32 + tid*8]);
    }
    short8 af[4], bfr[4];
#pragma unroll
    for (int mt = 0; mt < 4; mt++)
      af[mt] = *(const short8*)&As[buf][(wr*64 + mt*16 + l15)*32 + quad*8];
#pragma unroll
    for (int nt = 0; nt < 4; nt++)
      bfr[nt] = *(const short8*)&Bs[buf][(wc*64 + nt*16 + l15)*32 + quad*8];
#pragma unroll
    for (int mt = 0; mt < 4; mt++)
#pragma unroll
      for (int nt = 0; nt < 4; nt++)
        acc[mt][nt] = __builtin_amdgcn_mfma_f32_16x16x32_bf16(af[mt], bfr[nt], acc[mt][nt], 0, 0, 0);
    buf ^= 1;
  }

#pragma unroll
  for (int mt = 0; mt < 4; mt++){
    int grow = m0 + wr*64 + mt*16 + quad*4;
#pragma unroll
    for (int nt = 0; nt < 4; nt++){
      int gcol = n0 + wc*64 + nt*16 + l15;
      float bv = bias[gcol];
#pragma unroll
      for (int r = 0; r < 4; r++)
        Cout[(size_t)(grow + r)*N + gcol] = acc[mt][nt][r] + bv;
    }
  }
}

// ---------------- flash attention: 32x32 swapped QK^T, in-register P ----------------
// Grid 512 = 64 bh x 8 pairs, balanced (34 tiles/block), XCD-chunked (Did&7=XCD).
// Wave w owns 32 q-rows. Swapped QK^T: S^T = mfma32(K_frag, Q_frag) puts each
// lane's P-slice lane-local (q = lane&31, 32 k-values in regs). Softmax fully
// in-register: exp2(fma) + lane-local row sums (no shfl tree, no P-LDS).
// P -> PV A-frags via v_cvt_pk_bf16_f32 pairs + permlane32_swap (HK T12 recipe).
// K/V staged to LDS by global_load_lds (double-buffered, one barrier/tile,
// 16B-chunk XOR swizzle on global source + read side). LDS = 32 KB.
__global__ __launch_bounds__(256) void k_attn(const uint16_t* __restrict__ qkv,
                                              const uint16_t* __restrict__ vt,
                                              uint16_t* __restrict__ y){
  __shared__ __align__(16) uint16_t Klds[2][64*64];   // 16 KB
  __shared__ __align__(16) uint16_t Vlds[2][64*64];   // 16 KB

  const int Did = blockIdx.x;
  const int g = Did & 7, ii = Did >> 3;         // 64 blocks per XCD group
  const int bh = g*8 + (ii >> 3);               // 8 heads per XCD group
  const int X  = ii & 7;                        // pair index 0..7
  const int b = bh >> 4, h = bh & 15;
  const int lane = threadIdx.x & 63, w = threadIdx.x >> 6;
  const int l31 = lane & 31, hi = lane >> 5;

  const uint16_t* Qbase  = qkv + (size_t)b*2048*3072 + h*64;
  const uint16_t* Kbase  = qkv + (size_t)b*2048*3072 + 1024 + h*64;
  const uint16_t* Vtbase = vt  + (size_t)bh*64*2048;

  // softmax scale folded to base-2: p = 2^(s*S2 - M2); fixed shift cancels in l
  const float S2 = 0.18033688011112042f;        // 0.125 * log2(e)
  const float M2 = 43.28085122666890f;          // 30 * log2(e)

  // staging role: waves 0,1 stage K rows 0-31/32-63; waves 2,3 stage Vt rows (d)
  const int isV  = w >> 1;
  const int rbase = (w & 1) * 32;
  const int rsub = lane >> 3, csub = lane & 7;

  const int cA = X, cB = 15 - X;
  const int KT_A = 2*cA + 2;
  const int TS = 34;                            // uniform total steps

  int c = cA;
  int qr = c*128 + w*32;                        // wave's q-row base

  // Q B-frags (col=q=l31, k-elems d = kc*16 + hi*8 + j), live for the chunk
  short8 aq[4];
#pragma unroll
  for (int kc = 0; kc < 4; kc++)
    aq[kc] = *(const short8*)&Qbase[(size_t)(qr + l31)*3072 + kc*16 + hi*8];

  float16x o[2];
  o[0] = zero16(); o[1] = zero16();
  float lr4[4] = {0.f, 0.f, 0.f, 0.f};

  // per-chunk epilogue: combine halves' row sums, normalize, store
  auto epilogue = [&](){
    float l = (lr4[0] + lr4[1]) + (lr4[2] + lr4[3]);
    l += __shfl_xor(l, 32, 64);                 // full row sum for q = l31
    float linv = 1.f / l;
    float lv[16];
#pragma unroll
    for (int r = 0; r < 16; r++)
      lv[r] = __shfl(linv, (r&3) + 8*(r>>2) + 4*hi, 64);
#pragma unroll
    for (int dt = 0; dt < 2; dt++)
#pragma unroll
      for (int r = 0; r < 16; r++){
        int row = (r&3) + 8*(r>>2) + 4*hi;
        y[((size_t)(b*2048 + qr + row))*1024 + h*64 + dt*32 + l31] = f2b(o[dt][r] * lv[r]);
      }
  };

  // prologue: stage tile kt=0 into buf 0 (source chunk pre-swizzled; LDS linear)
#pragma unroll
  for (int j = 0; j < 4; j++){
    int r  = rbase + j*8 + rsub;
    int cg = csub ^ (r & 7);
    if (isV) gload16(Vtbase + (size_t)r*2048 + cg*8, &Vlds[0][(rbase + j*8)*64 + lane*8]);
    else     gload16(Kbase  + (size_t)r*3072 + cg*8, &Klds[0][(rbase + j*8)*64 + lane*8]);
  }

  int cur = 0;
  for (int t = 0; t < TS; ++t){
    __syncthreads();                            // buf[cur] staged; buf[cur^1] free
    const int kt = (t < KT_A) ? t : t - KT_A;
    if (t + 1 < TS){
      const int ktn = (t + 1 < KT_A) ? t + 1 : t + 1 - KT_A;  // chunk boundary -> 0
      int nb = cur ^ 1;
#pragma unroll
      for (int j = 0; j < 4; j++){
        int r  = rbase + j*8 + rsub;
        int cg = csub ^ (r & 7);
        if (isV) gload16(Vtbase + (size_t)r*2048 + (size_t)ktn*64 + cg*8,
                         &Vlds[nb][(rbase + j*8)*64 + lane*8]);
        else     gload16(Kbase  + (size_t)(ktn*64 + r)*3072 + cg*8,
                         &Klds[nb][(rbase + j*8)*64 + lane*8]);
      }
    }

    if (t == KT_A){
      // chunk A done: emit it, switch to chunk B (wave-uniform branch)
      epilogue();
      c = cB; qr = c*128 + w*32;
#pragma unroll
      for (int kc = 0; kc < 4; kc++)
        aq[kc] = *(const short8*)&Qbase[(size_t)(qr + l31)*3072 + kc*16 + hi*8];
      o[0] = zero16(); o[1] = zero16();
      lr4[0] = lr4[1] = lr4[2] = lr4[3] = 0.f;
    }

    // ---- swapped QK^T: S^T[kpos][q] (p0: kpos 0-31, p1: 32-63) ----
    float16x p0 = zero16(), p1 = zero16();
    __builtin_amdgcn_s_setprio(1);
#pragma unroll
    for (int kc = 0; kc < 4; kc++){
      const int ch = 2*kc + hi;
      short8 ak0 = *(const short8*)&Klds[cur][(l31)*64      + ((ch ^ (l31 & 7))*8)];
      short8 ak1 = *(const short8*)&Klds[cur][(32 + l31)*64 + ((ch ^ (l31 & 7))*8)];
      p0 = __builtin_amdgcn_mfma_f32_32x32x16_bf16(ak0, aq[kc], p0, 0, 0, 0);
      p1 = __builtin_amdgcn_mfma_f32_32x32x16_bf16(ak1, aq[kc], p1, 0, 0, 0);
    }
    __builtin_amdgcn_s_setprio(0);

    // causal mask: only the last two steps of each chunk cross the diagonal
    if (kt >= 2*c){
      const int tq = qr + l31;
#pragma unroll
      for (int r = 0; r < 16; r++){
        int kb = kt*64 + (r&3) + 8*(r>>2) + 4*hi;
        if (kb > tq)      p0[r] = -1e30f;
        if (kb + 32 > tq) p1[r] = -1e30f;
      }
    }

    // softmax: p = exp2(s*S2 - M2), lane-local row sums
#pragma unroll
    for (int r = 0; r < 16; r++){
      float e0 = fexp2(__builtin_fmaf(p0[r], S2, -M2));
      float e1 = fexp2(__builtin_fmaf(p1[r], S2, -M2));
      lr4[r & 3] += e0 + e1;
      p0[r] = e0; p1[r] = e1;
    }

    // ---- PV: per K16-chunk build A-frag in-register (cvt_pk + permlane32_swap) ----
    __builtin_amdgcn_s_setprio(1);
#pragma unroll
    for (int kc = 0; kc < 4; kc++){
      const int e8 = (kc & 1)*8;
      uint32_t w0, w1, w2, w3;
      if (kc < 2){
        w0 = cvtpk(p0[e8+0], p0[e8+1]); w1 = cvtpk(p0[e8+2], p0[e8+3]);
        w2 = cvtpk(p0[e8+4], p0[e8+5]); w3 = cvtpk(p0[e8+6], p0[e8+7]);
      } else {
        w0 = cvtpk(p1[e8+0], p1[e8+1]); w1 = cvtpk(p1[e8+2], p1[e8+3]);
        w2 = cvtpk(p1[e8+4], p1[e8+5]); w3 = cvtpk(p1[e8+6], p1[e8+7]);
      }
      plswap(w0, w2);                           // (w0,w2): halves exchanged
      plswap(w1, w3);
      union { uint32_t u[4]; short8 s; } ap;
      ap.u[0] = w0; ap.u[1] = w1; ap.u[2] = w2; ap.u[3] = w3;

      const int ch = 2*kc + hi;
      short8 bv0 = *(const short8*)&Vlds[cur][(l31)*64      + ((ch ^ (l31 & 7))*8)];
      short8 bv1 = *(const short8*)&Vlds[cur][(32 + l31)*64 + ((ch ^ (l31 & 7))*8)];
      o[0] = __builtin_amdgcn_mfma_f32_32x32x16_bf16(ap.s, bv0, o[0], 0, 0, 0);
      o[1] = __builtin_amdgcn_mfma_f32_32x32x16_bf16(ap.s, bv1, o[1], 0, 0, 0);
    }
    __builtin_amdgcn_s_setprio(0);
    cur ^= 1;
  }

  epilogue();                                   // chunk B
}

extern "C" void kernel_launch(void* const* d_in, const int* in_sizes, int n_in,
                              void* d_out, int out_size, void* d_ws, size_t ws_size,
                              hipStream_t stream){
  const float* x     = (const float*)d_in[0];
  const float* Wqkv  = (const float*)d_in[1];
  const float* bqkv  = (const float*)d_in[2];
  const float* Wproj = (const float*)d_in[3];
  const float* bproj = (const float*)d_in[4];

  uint16_t* p = (uint16_t*)d_ws;
  uint16_t* xb    = p; p += (size_t)8192*1024;   // x in bf16
  uint16_t* wqkvt = p; p += (size_t)3072*1024;   // W_qkv^T bf16
  uint16_t* wprjt = p; p += (size_t)1024*1024;   // W_proj^T bf16
  uint16_t* qkv   = p; p += (size_t)8192*3072;   // q,k rope'd (V third unused)
  uint16_t* vt    = p; p += (size_t)64*64*2048;  // V^T per head [bh][d][t]
  uint16_t* yb    = p; p += (size_t)8192*1024;   // attention output bf16

  k_f32_to_bf16<<<8192, 256, 0, stream>>>(x, xb, 2097152);
  k_transpose_bf16<<<dim3(96, 32), 256, 0, stream>>>(Wqkv, wqkvt, 1024, 3072);
  k_transpose_bf16<<<dim3(32, 32), 256, 0, stream>>>(Wproj, wprjt, 1024, 1024);
  k_gemm_qkv<<<dim3(24, 64), 256, 0, stream>>>(xb, wqkvt, bqkv, qkv, vt);
  k_attn<<<512, 256, 0, stream>>>(qkv, vt, yb);
  k_gemm_proj<<<dim3(8, 64), 256, 0, stream>>>(yb, wprjt, bproj, (float*)d_out, 8192, 1024, 1024);
}

// Round 7
// 251.920 us; speedup vs baseline: 2.2544x; 1.0382x over previous
//
#include <hip/hip_runtime.h>
#include <cstdint>
#include <cstddef>

typedef __attribute__((ext_vector_type(8))) short short8;
typedef __attribute__((ext_vector_type(4))) float float4x;
typedef __attribute__((ext_vector_type(16))) float float16x;
typedef __attribute__((ext_vector_type(2))) unsigned int uint2v;

__device__ __forceinline__ uint16_t f2b(float f){
  uint32_t u = __builtin_bit_cast(uint32_t, f);
  u += 0x7FFFu + ((u >> 16) & 1u);
  return (uint16_t)(u >> 16);
}
__device__ __forceinline__ float b2f(uint16_t h){
  uint32_t u = ((uint32_t)h) << 16;
  return __builtin_bit_cast(float, u);
}
__device__ __forceinline__ float4x zero4(){
  float4x v; v[0]=0.f; v[1]=0.f; v[2]=0.f; v[3]=0.f; return v;
}
__device__ __forceinline__ float16x zero16(){
  float16x v;
#pragma unroll
  for (int i = 0; i < 16; i++) v[i] = 0.f;
  return v;
}
// packed f32x2 -> bf16x2 (RNE), one instruction
__device__ __forceinline__ uint32_t cvtpk(float lo, float hi){
  uint32_t r;
  asm("v_cvt_pk_bf16_f32 %0, %1, %2" : "=v"(r) : "v"(lo), "v"(hi));
  return r;
}
// swap a[32:63] <-> b[0:31] (HK T12 recipe). Fallback: shfl_xor emulation.
__device__ __forceinline__ void plswap(uint32_t &a, uint32_t &b){
#if __has_builtin(__builtin_amdgcn_permlane32_swap)
  uint2v r = __builtin_amdgcn_permlane32_swap(a, b, false, false);
  a = r[0]; b = r[1];
#else
  uint32_t a2 = (uint32_t)__shfl_xor((int)a, 32, 64);
  uint32_t b2 = (uint32_t)__shfl_xor((int)b, 32, 64);
  bool lo = ((threadIdx.x & 63) < 32);
  uint32_t an = lo ? a : b2;
  uint32_t bn = lo ? a2 : b;
  a = an; b = bn;
#endif
}
__device__ __forceinline__ float fexp2(float x){
#if __has_builtin(__builtin_amdgcn_exp2f)
  return __builtin_amdgcn_exp2f(x);
#else
  return exp2f(x);
#endif
}
// async global->LDS, 16B per lane. LDS dest = wave-uniform base + lane*16.
__device__ __forceinline__ void gload16(const uint16_t* g, uint16_t* l){
  __builtin_amdgcn_global_load_lds(
      (const __attribute__((address_space(1))) uint32_t*)g,
      (__attribute__((address_space(3))) uint32_t*)l, 16, 0, 0);
}

// ---------------- x (f32) -> bf16 ----------------
__global__ __launch_bounds__(256) void k_f32_to_bf16(const float* __restrict__ in,
                                                     uint16_t* __restrict__ out, int n4){
  int i = blockIdx.x * 256 + threadIdx.x;
  if (i < n4){
    float4 v = ((const float4*)in)[i];
    ushort4 o;
    o.x = f2b(v.x); o.y = f2b(v.y); o.z = f2b(v.z); o.w = f2b(v.w);
    ((ushort4*)out)[i] = o;
  }
}

// ---------------- W [K][N] f32 -> Wt [N][K] bf16 ----------------
__global__ __launch_bounds__(256) void k_transpose_bf16(const float* __restrict__ W,
                                                        uint16_t* __restrict__ Wt, int K, int N){
  __shared__ float tile[32][33];
  int k0 = blockIdx.y * 32, n0 = blockIdx.x * 32;
  int c = threadIdx.x & 31, r0 = threadIdx.x >> 5;
  for (int rr = r0; rr < 32; rr += 8)
    tile[rr][c] = W[(size_t)(k0 + rr) * N + n0 + c];
  __syncthreads();
  for (int rr = r0; rr < 32; rr += 8)
    Wt[(size_t)(n0 + rr) * K + k0 + c] = f2b(tile[c][rr]);
}

// ---------------- fused QKV GEMM: qkv = x*Wqkv + b, RoPE(q,k) in-epilogue,
// ---------------- V written directly transposed to vt [bh][d][t] ----------------
__global__ __launch_bounds__(256, 3) void k_gemm_qkv(const uint16_t* __restrict__ A,
                                                     const uint16_t* __restrict__ Bt,
                                                     const float* __restrict__ bias,
                                                     uint16_t* __restrict__ qkv,
                                                     uint16_t* __restrict__ vt){
  const int K = 1024;
  __shared__ __align__(16) uint16_t SM[18432];        // As:[0,8192) Bs:[8192,16384); T: per-wave 4608
  uint16_t* As_ = SM;
  uint16_t* Bs_ = SM + 8192;
  const int tid = threadIdx.x, lane = tid & 63, wave = tid >> 6;
  const int wr = wave >> 1, wc = wave & 1;
  const int m0 = blockIdx.y * 128, n0 = blockIdx.x * 128;
  const int quad = lane >> 4, l15 = lane & 15;
  const int rowA = tid >> 2, chA = tid & 3;

  float4x acc[4][4];
  for (int i = 0; i < 4; i++) for (int j = 0; j < 4; j++) acc[i][j] = zero4();

  const uint16_t* pa0 = &A[(size_t)(m0 + rowA)*K + chA*8];
  const uint16_t* pa1 = &A[(size_t)(m0 + rowA + 64)*K + chA*8];
  const uint16_t* pb0 = &Bt[(size_t)(n0 + rowA)*K + chA*8];
  const uint16_t* pb1 = &Bt[(size_t)(n0 + rowA + 64)*K + chA*8];

  gload16(pa0, &As_[tid*8]);
  gload16(pa1, &As_[64*32 + tid*8]);
  gload16(pb0, &Bs_[tid*8]);
  gload16(pb1, &Bs_[64*32 + tid*8]);

  int buf = 0;
  for (int k0 = 0; k0 < K; k0 += 32){
    __syncthreads();
    if (k0 + 32 < K){
      int nb = buf ^ 1;
      gload16(pa0 + k0 + 32, &As_[nb*4096 + tid*8]);
      gload16(pa1 + k0 + 32, &As_[nb*4096 + 64*32 + tid*8]);
      gload16(pb0 + k0 + 32, &Bs_[nb*4096 + tid*8]);
      gload16(pb1 + k0 + 32, &Bs_[nb*4096 + 64*32 + tid*8]);
    }
    short8 af[4], bfr[4];
#pragma unroll
    for (int mt = 0; mt < 4; mt++)
      af[mt] = *(const short8*)&As_[buf*4096 + (wr*64 + mt*16 + l15)*32 + quad*8];
#pragma unroll
    for (int nt = 0; nt < 4; nt++)
      bfr[nt] = *(const short8*)&Bs_[buf*4096 + (wc*64 + nt*16 + l15)*32 + quad*8];
#pragma unroll
    for (int mt = 0; mt < 4; mt++)
#pragma unroll
      for (int nt = 0; nt < 4; nt++)
        acc[mt][nt] = __builtin_amdgcn_mfma_f32_16x16x32_bf16(af[mt], bfr[nt], acc[mt][nt], 0, 0, 0);
    buf ^= 1;
  }

  if (blockIdx.x < 16){
    // ---- q,k halves: bias + RoPE in-register, write to qkv ----
#pragma unroll
    for (int mt = 0; mt < 4; mt++){
      int grow = m0 + wr*64 + mt*16 + quad*4;
      int tpos = grow & 2047;                    // batch-local position
#pragma unroll
      for (int nt = 0; nt < 2; nt++){
        int gcol = n0 + wc*64 + nt*16 + l15;
        float bv1 = bias[gcol], bv2 = bias[gcol + 32];
        int i = nt*16 + l15;                     // head-local index 0..31
        float inv = exp2f(-(float)i * 0.4152410118609203f);  // 10000^(-i/32)
#pragma unroll
        for (int r = 0; r < 4; r++){
          float ang = (float)(tpos + r) * inv;
          float s, c;
          __sincosf(ang, &s, &c);
          float u1 = acc[mt][nt][r]   + bv1;
          float u2 = acc[mt][nt+2][r] + bv2;
          qkv[(size_t)(grow + r)*3072 + gcol]      = f2b(u1*c - u2*s);
          qkv[(size_t)(grow + r)*3072 + gcol + 32] = f2b(u2*c + u1*s);
        }
      }
    }
  } else {
    // ---- v half: bias, transpose 64x64 per wave through LDS, write vt[d][t] ----
    __syncthreads();                             // all waves done reading As/Bs
    uint16_t* T = &SM[wave*4608];                // [64 d][72] (stride 144 B)
#pragma unroll
    for (int mt = 0; mt < 4; mt++)
#pragma unroll
      for (int nt = 0; nt < 4; nt++){
        int gcol = n0 + wc*64 + nt*16 + l15;
        float bv = bias[gcol];
#pragma unroll
        for (int r = 0; r < 4; r++)
          T[(nt*16 + l15)*72 + mt*16 + quad*4 + r] = f2b(acc[mt][nt][r] + bv);
      }
    __syncthreads();                             // writes visible (block-uniform barrier)
    const int h = (n0 + wc*64 - 2048) >> 6;
    const int tg0 = m0 + wr*64;
    const int bb = tg0 >> 11, tb = tg0 & 2047;
    const int bh64 = (bb*16 + h)*64;
    const int d32 = lane & 31, th = lane >> 5;
#pragma unroll
    for (int dd = 0; dd < 2; dd++)
#pragma unroll
      for (int it = 0; it < 4; it++){
        short8 v = *(const short8*)&T[(d32 + 32*dd)*72 + th*32 + it*8];
        *(short8*)&vt[((size_t)(bh64 + d32 + 32*dd))*2048 + tb + th*32 + it*8] = v;
      }
  }
}

// ---------------- bf16 GEMM: C = A[m][k] * Bt[n][k] + bias (f32 out), 128x128 tile ----------------
__global__ __launch_bounds__(256, 3) void k_gemm_proj(const uint16_t* __restrict__ A,
                                                      const uint16_t* __restrict__ Bt,
                                                      const float* __restrict__ bias,
                                                      float* __restrict__ Cout,
                                                      int M, int N, int K){
  __shared__ __align__(16) uint16_t As[2][128*32];
  __shared__ __align__(16) uint16_t Bs[2][128*32];
  const int tid = threadIdx.x, lane = tid & 63, wave = tid >> 6;
  const int wr = wave >> 1, wc = wave & 1;
  const int m0 = blockIdx.y * 128, n0 = blockIdx.x * 128;
  const int quad = lane >> 4, l15 = lane & 15;
  const int rowA = tid >> 2, chA = tid & 3;

  float4x acc[4][4];
  for (int i = 0; i < 4; i++) for (int j = 0; j < 4; j++) acc[i][j] = zero4();

  const uint16_t* pa0 = &A[(size_t)(m0 + rowA)*K + chA*8];
  const uint16_t* pa1 = &A[(size_t)(m0 + rowA + 64)*K + chA*8];
  const uint16_t* pb0 = &Bt[(size_t)(n0 + rowA)*K + chA*8];
  const uint16_t* pb1 = &Bt[(size_t)(n0 + rowA + 64)*K + chA*8];

  gload16(pa0, &As[0][tid*8]);
  gload16(pa1, &As[0][64*32 + tid*8]);
  gload16(pb0, &Bs[0][tid*8]);
  gload16(pb1, &Bs[0][64*32 + tid*8]);

  int buf = 0;
  for (int k0 = 0; k0 < K; k0 += 32){
    __syncthreads();
    if (k0 + 32 < K){
      int nb = buf ^ 1;
      gload16(pa0 + k0 + 32, &As[nb][tid*8]);
      gload16(pa1 + k0 + 32, &As[nb][64*32 + tid*8]);
      gload16(pb0 + k0 + 32, &Bs[nb][tid*8]);
      gload16(pb1 + k0 + 32, &Bs[nb][64*32 + tid*8]);
    }
    short8 af[4], bfr[4];
#pragma unroll
    for (int mt = 0; mt < 4; mt++)
      af[mt] = *(const short8*)&As[buf][(wr*64 + mt*16 + l15)*32 + quad*8];
#pragma unroll
    for (int nt = 0; nt < 4; nt++)
      bfr[nt] = *(const short8*)&Bs[buf][(wc*64 + nt*16 + l15)*32 + quad*8];
#pragma unroll
    for (int mt = 0; mt < 4; mt++)
#pragma unroll
      for (int nt = 0; nt < 4; nt++)
        acc[mt][nt] = __builtin_amdgcn_mfma_f32_16x16x32_bf16(af[mt], bfr[nt], acc[mt][nt], 0, 0, 0);
    buf ^= 1;
  }

#pragma unroll
  for (int mt = 0; mt < 4; mt++){
    int grow = m0 + wr*64 + mt*16 + quad*4;
#pragma unroll
    for (int nt = 0; nt < 4; nt++){
      int gcol = n0 + wc*64 + nt*16 + l15;
      float bv = bias[gcol];
#pragma unroll
      for (int r = 0; r < 4; r++)
        Cout[(size_t)(grow + r)*N + gcol] = acc[mt][nt][r] + bv;
    }
  }
}

// ---------------- flash attention: 8-wave blocks, 32x32 swapped QK^T, in-register P ----------------
// m214 8-warp geometry: 256 q-rows/block (8 waves x 32), KVBLK=64. Grid 256 =
// 64 bh x 4 pairs; pair (X, 7-X) of 256-row chunks, KT(c) = 4c+4 -> uniform 36
// steps/block. vs the 4-wave version this HALVES per-CU staging volume, gload
// count and barrier count (68 -> 36 block-steps/CU) at identical per-wave tile
// work. XCD-chunked: Did&7 = XCD, 8 heads/XCD (K/V 4MB = its L2).
// Waves 0-3 stage K rows (16 each), waves 4-7 stage Vt d-rows (16 each):
// 2 gload16/wave/step, 16B-chunk XOR swizzle on global source + read side.
// Per-wave uniform skip of fully-masked tiles (kt*64 > qr+31); mask loop only
// when the tile straddles this wave's diagonal. Fixed-max softmax (exact cancel).
__global__ __launch_bounds__(512) void k_attn(const uint16_t* __restrict__ qkv,
                                              const uint16_t* __restrict__ vt,
                                              uint16_t* __restrict__ y){
  __shared__ __align__(16) uint16_t Klds[2][64*64];   // 16 KB
  __shared__ __align__(16) uint16_t Vlds[2][64*64];   // 16 KB

  const int Did = blockIdx.x;
  const int g = Did & 7, ii = Did >> 3;         // 32 blocks per XCD
  const int bh = g*8 + (ii >> 2);               // 8 heads per XCD
  const int X  = ii & 3;                        // pair index 0..3
  const int b = bh >> 4, h = bh & 15;
  const int lane = threadIdx.x & 63, w = threadIdx.x >> 6;   // 8 waves
  const int l31 = lane & 31, hi = lane >> 5;

  const uint16_t* Qbase  = qkv + (size_t)b*2048*3072 + h*64;
  const uint16_t* Kbase  = qkv + (size_t)b*2048*3072 + 1024 + h*64;
  const uint16_t* Vtbase = vt  + (size_t)bh*64*2048;

  // softmax scale folded to base-2: p = 2^(s*S2 - M2); fixed shift cancels in l
  const float S2 = 0.18033688011112042f;        // 0.125 * log2(e)
  const float M2 = 43.28085122666890f;          // 30 * log2(e)

  // staging role: waves 0-3 stage K rows (16 each); waves 4-7 stage Vt d-rows
  const int isV  = w >> 2;
  const int rbase = (w & 3) * 16;
  const int rsub = lane >> 3, csub = lane & 7;

  const int cA = X, cB = 7 - X;
  const int KT_A = 4*cA + 4;
  const int TS = 36;                            // uniform total steps

  int c = cA;
  int qr = c*256 + w*32;                        // wave's q-row base

  // Q B-frags (col=q=l31, k-elems d = kc*16 + hi*8 + j), live for the chunk
  short8 aq[4];
#pragma unroll
  for (int kc = 0; kc < 4; kc++)
    aq[kc] = *(const short8*)&Qbase[(size_t)(qr + l31)*3072 + kc*16 + hi*8];

  float16x o[2];
  o[0] = zero16(); o[1] = zero16();
  float lr4[4] = {0.f, 0.f, 0.f, 0.f};

  // per-chunk epilogue: combine halves' row sums, normalize, store
  auto epilogue = [&](){
    float l = (lr4[0] + lr4[1]) + (lr4[2] + lr4[3]);
    l += __shfl_xor(l, 32, 64);                 // full row sum for q = l31
    float linv = 1.f / l;
    float lv[16];
#pragma unroll
    for (int r = 0; r < 16; r++)
      lv[r] = __shfl(linv, (r&3) + 8*(r>>2) + 4*hi, 64);
#pragma unroll
    for (int dt = 0; dt < 2; dt++)
#pragma unroll
      for (int r = 0; r < 16; r++){
        int row = (r&3) + 8*(r>>2) + 4*hi;
        y[((size_t)(b*2048 + qr + row))*1024 + h*64 + dt*32 + l31] = f2b(o[dt][r] * lv[r]);
      }
  };

  // prologue: stage tile kt=0 into buf 0 (source chunk pre-swizzled; LDS linear)
#pragma unroll
  for (int j = 0; j < 2; j++){
    int r  = rbase + j*8 + rsub;
    int cg = csub ^ (r & 7);
    if (isV) gload16(Vtbase + (size_t)r*2048 + cg*8, &Vlds[0][(rbase + j*8)*64 + lane*8]);
    else     gload16(Kbase  + (size_t)r*3072 + cg*8, &Klds[0][(rbase + j*8)*64 + lane*8]);
  }

  int cur = 0;
  for (int t = 0; t < TS; ++t){
    __syncthreads();                            // buf[cur] staged; buf[cur^1] free
    const int kt = (t < KT_A) ? t : t - KT_A;
    if (t + 1 < TS){
      const int ktn = (t + 1 < KT_A) ? t + 1 : t + 1 - KT_A;  // chunk boundary -> 0
      int nb = cur ^ 1;
#pragma unroll
      for (int j = 0; j < 2; j++){
        int r  = rbase + j*8 + rsub;
        int cg = csub ^ (r & 7);
        if (isV) gload16(Vtbase + (size_t)r*2048 + (size_t)ktn*64 + cg*8,
                         &Vlds[nb][(rbase + j*8)*64 + lane*8]);
        else     gload16(Kbase  + (size_t)(ktn*64 + r)*3072 + cg*8,
                         &Klds[nb][(rbase + j*8)*64 + lane*8]);
      }
    }

    if (t == KT_A){
      // chunk A done: emit it, switch to chunk B (block-uniform branch)
      epilogue();
      c = cB; qr = c*256 + w*32;
#pragma unroll
      for (int kc = 0; kc < 4; kc++)
        aq[kc] = *(const short8*)&Qbase[(size_t)(qr + l31)*3072 + kc*16 + hi*8];
      o[0] = zero16(); o[1] = zero16();
      lr4[0] = lr4[1] = lr4[2] = lr4[3] = 0.f;
    }

    // wave-uniform skip: tile entirely above this wave's diagonal -> contributes 0
    if (kt*64 <= qr + 31){
      // ---- swapped QK^T: S^T[kpos][q] (p0: kpos 0-31, p1: 32-63) ----
      float16x p0 = zero16(), p1 = zero16();
      __builtin_amdgcn_s_setprio(1);
#pragma unroll
      for (int kc = 0; kc < 4; kc++){
        const int ch = 2*kc + hi;
        short8 ak0 = *(const short8*)&Klds[cur][(l31)*64      + ((ch ^ (l31 & 7))*8)];
        short8 ak1 = *(const short8*)&Klds[cur][(32 + l31)*64 + ((ch ^ (l31 & 7))*8)];
        p0 = __builtin_amdgcn_mfma_f32_32x32x16_bf16(ak0, aq[kc], p0, 0, 0, 0);
        p1 = __builtin_amdgcn_mfma_f32_32x32x16_bf16(ak1, aq[kc], p1, 0, 0, 0);
      }
      __builtin_amdgcn_s_setprio(0);

      // causal mask: only tiles straddling this wave's diagonal
      if (kt*64 + 63 > qr){
        const int tq = qr + l31;
#pragma unroll
        for (int r = 0; r < 16; r++){
          int kb = kt*64 + (r&3) + 8*(r>>2) + 4*hi;
          if (kb > tq)      p0[r] = -1e30f;
          if (kb + 32 > tq) p1[r] = -1e30f;
        }
      }

      // softmax: p = exp2(s*S2 - M2), lane-local row sums
#pragma unroll
      for (int r = 0; r < 16; r++){
        float e0 = fexp2(__builtin_fmaf(p0[r], S2, -M2));
        float e1 = fexp2(__builtin_fmaf(p1[r], S2, -M2));
        lr4[r & 3] += e0 + e1;
        p0[r] = e0; p1[r] = e1;
      }

      // ---- PV: per K16-chunk build A-frag in-register (cvt_pk + permlane32_swap) ----
      __builtin_amdgcn_s_setprio(1);
#pragma unroll
      for (int kc = 0; kc < 4; kc++){
        const int e8 = (kc & 1)*8;
        uint32_t w0, w1, w2, w3;
        if (kc < 2){
          w0 = cvtpk(p0[e8+0], p0[e8+1]); w1 = cvtpk(p0[e8+2], p0[e8+3]);
          w2 = cvtpk(p0[e8+4], p0[e8+5]); w3 = cvtpk(p0[e8+6], p0[e8+7]);
        } else {
          w0 = cvtpk(p1[e8+0], p1[e8+1]); w1 = cvtpk(p1[e8+2], p1[e8+3]);
          w2 = cvtpk(p1[e8+4], p1[e8+5]); w3 = cvtpk(p1[e8+6], p1[e8+7]);
        }
        plswap(w0, w2);                         // (w0,w2): halves exchanged
        plswap(w1, w3);
        union { uint32_t u[4]; short8 s; } ap;
        ap.u[0] = w0; ap.u[1] = w1; ap.u[2] = w2; ap.u[3] = w3;

        const int ch = 2*kc + hi;
        short8 bv0 = *(const short8*)&Vlds[cur][(l31)*64      + ((ch ^ (l31 & 7))*8)];
        short8 bv1 = *(const short8*)&Vlds[cur][(32 + l31)*64 + ((ch ^ (l31 & 7))*8)];
        o[0] = __builtin_amdgcn_mfma_f32_32x32x16_bf16(ap.s, bv0, o[0], 0, 0, 0);
        o[1] = __builtin_amdgcn_mfma_f32_32x32x16_bf16(ap.s, bv1, o[1], 0, 0, 0);
      }
      __builtin_amdgcn_s_setprio(0);
    }
    cur ^= 1;
  }

  epilogue();                                   // chunk B
}

extern "C" void kernel_launch(void* const* d_in, const int* in_sizes, int n_in,
                              void* d_out, int out_size, void* d_ws, size_t ws_size,
                              hipStream_t stream){
  const float* x     = (const float*)d_in[0];
  const float* Wqkv  = (const float*)d_in[1];
  const float* bqkv  = (const float*)d_in[2];
  const float* Wproj = (const float*)d_in[3];
  const float* bproj = (const float*)d_in[4];

  uint16_t* p = (uint16_t*)d_ws;
  uint16_t* xb    = p; p += (size_t)8192*1024;   // x in bf16
  uint16_t* wqkvt = p; p += (size_t)3072*1024;   // W_qkv^T bf16
  uint16_t* wprjt = p; p += (size_t)1024*1024;   // W_proj^T bf16
  uint16_t* qkv   = p; p += (size_t)8192*3072;   // q,k rope'd (V third unused)
  uint16_t* vt    = p; p += (size_t)64*64*2048;  // V^T per head [bh][d][t]
  uint16_t* yb    = p; p += (size_t)8192*1024;   // attention output bf16

  k_f32_to_bf16<<<8192, 256, 0, stream>>>(x, xb, 2097152);
  k_transpose_bf16<<<dim3(96, 32), 256, 0, stream>>>(Wqkv, wqkvt, 1024, 3072);
  k_transpose_bf16<<<dim3(32, 32), 256, 0, stream>>>(Wproj, wprjt, 1024, 1024);
  k_gemm_qkv<<<dim3(24, 64), 256, 0, stream>>>(xb, wqkvt, bqkv, qkv, vt);
  k_attn<<<256, 512, 0, stream>>>(qkv, vt, yb);
  k_gemm_proj<<<dim3(8, 64), 256, 0, stream>>>(yb, wprjt, bproj, (float*)d_out, 8192, 1024, 1024);
}